// Round 2
// 508.646 us; speedup vs baseline: 1.0201x; 1.0201x over previous
//
#include <hip/hip_runtime.h>
#include <stdint.h>

#define NE   1024
#define ED   256
#define NB   2
#define S    32768            // 32*32*32
#define TOKENS (NB*S)         // 65536

#define OFF_LOSS 16777216
#define OFF_IDX  16777217
#define OFF_SAMP 16842753
#define OFF_MD   16844801
#define OFF_MV   16844802

#define TAU 2.5e-4f           // fp16-filter ambiguity margin (~6 sigma of 3e-5 err)

typedef _Float16 half8 __attribute__((ext_vector_type(8)));
typedef float floatx4 __attribute__((ext_vector_type(4)));

// ---------------- codebook norms: bitwise numpy pairwise sum ----------------
__global__ void k_enorm(const float* __restrict__ emb, float* __restrict__ en) {
#pragma clang fp contract(off)
  int j = blockIdx.x * 256 + threadIdx.x;
  const float* e = emb + (size_t)j * ED;
  float halves[2];
  for (int h = 0; h < 2; ++h) {
    const float* a = e + h * 128;
    float r[8];
    for (int k = 0; k < 8; ++k) r[k] = a[k] * a[k];
    for (int i = 8; i < 128; i += 8)
      for (int k = 0; k < 8; ++k) r[k] += a[i + k] * a[i + k];
    halves[h] = ((r[0] + r[1]) + (r[2] + r[3])) + ((r[4] + r[5]) + (r[6] + r[7]));
  }
  en[j] = halves[0] + halves[1];
}

// ---------------- emb -> fragment-ordered fp16 ----------------
__global__ void k_cvt(const float* __restrict__ emb, _Float16* __restrict__ embf) {
  int g = blockIdx.x * 512 + threadIdx.x;   // 64 blocks x 512 = 32768
  int lane = g & 63;
  int ks = (g >> 6) & 7;
  int nt = g >> 9;
  int n = nt * 16 + (lane & 15);
  int k0 = ks * 32 + (lane >> 4) * 8;
  const float* src = emb + (size_t)n * ED + k0;
  half8 v;
#pragma unroll
  for (int j = 0; j < 8; ++j) v[j] = (_Float16)src[j];
  *(half8*)(embf + ((size_t)((nt * 8 + ks) * 64 + lane)) * 8) = v;
}

// ---------------- MFMA filter: approx argmin + top-2 ambiguity ----------------
// 128 tokens/block, 256 thr = 4 waves; wave w owns tokens [w*32, w*32+32)
// (2 m-stripes of 16). Sweeps all 1024 codes via 64 n-tiles of 16x16x32 mfma.
__global__ void __launch_bounds__(256)
k_filter(const float* __restrict__ z, const _Float16* __restrict__ embf,
         const float* __restrict__ en, float* __restrict__ out_idx,
         int* __restrict__ amb_cnt, int* __restrict__ amb_list) {
  __shared__ _Float16 zA[128 * 264];   // [tok][c], stride 264 -> 2-way banks
  __shared__ float en_s[NE];

  int tid = threadIdx.x;
  int lane = tid & 63;
  int w = tid >> 6;
  int mrow = lane & 15;
  int quad = lane >> 4;
  int t0 = blockIdx.x * 128;
  int b = t0 >> 15;                    // 32768 % 128 == 0: no straddle
  int s0 = t0 & 32767;

  for (int i = tid; i < NE; i += 256) en_s[i] = en[i];

  {  // stage z tile -> fp16 LDS (coalesced along s, rne convert)
    int tok = tid & 127;
    int ch = tid >> 7;
    const float* zb = z + (size_t)b * ED * S + s0 + tok;
    for (int it = 0; it < 16; ++it) {
      int c0 = ch * 8 + it * 16;
      half8 v;
#pragma unroll
      for (int j = 0; j < 8; ++j) v[j] = (_Float16)zb[(size_t)(c0 + j) * S];
      *(half8*)(&zA[tok * 264 + c0]) = v;
    }
  }
  __syncthreads();

  // A-frags register-resident: af[stripe][kstep]
  half8 af[2][8];
#pragma unroll
  for (int s = 0; s < 2; ++s)
#pragma unroll
    for (int ks = 0; ks < 8; ++ks)
      af[s][ks] = *(const half8*)(&zA[(w * 32 + s * 16 + mrow) * 264 + ks * 32 + quad * 8]);

  float m1[2][4], m2[2][4];
  int j1[2][4];
#pragma unroll
  for (int s = 0; s < 2; ++s)
#pragma unroll
    for (int r = 0; r < 4; ++r) { m1[s][r] = 3.4e38f; m2[s][r] = 3.4e38f; j1[s][r] = 0; }

  for (int nt = 0; nt < 64; ++nt) {
    floatx4 acc0 = {0.f, 0.f, 0.f, 0.f}, acc1 = {0.f, 0.f, 0.f, 0.f};
    const half8* pb = (const half8*)(embf + ((size_t)(nt * 8) * 64 + lane) * 8);
#pragma unroll
    for (int ks = 0; ks < 8; ++ks) {
      half8 bf = pb[ks * 64];          // coalesced 16B/lane from L2
      acc0 = __builtin_amdgcn_mfma_f32_16x16x32_f16(af[0][ks], bf, acc0, 0, 0, 0);
      acc1 = __builtin_amdgcn_mfma_f32_16x16x32_f16(af[1][ks], bf, acc1, 0, 0, 0);
    }
    int j = nt * 16 + mrow;
    float Bj = en_s[j];                // ||z||^2 constant per token -> dropped
#pragma unroll
    for (int r = 0; r < 4; ++r) {
      float d0 = Bj - 2.f * acc0[r];
      float d1 = Bj - 2.f * acc1[r];
      if (d0 < m1[0][r]) { m2[0][r] = m1[0][r]; m1[0][r] = d0; j1[0][r] = j; }
      else if (d0 < m2[0][r]) m2[0][r] = d0;
      if (d1 < m1[1][r]) { m2[1][r] = m1[1][r]; m1[1][r] = d1; j1[1][r] = j; }
      else if (d1 < m2[1][r]) m2[1][r] = d1;
    }
  }

  // merge across the 16 lanes of each quad (same tokens, different codes)
#pragma unroll
  for (int d = 1; d < 16; d <<= 1) {
#pragma unroll
    for (int s = 0; s < 2; ++s)
#pragma unroll
      for (int r = 0; r < 4; ++r) {
        float om1 = __shfl_xor(m1[s][r], d, 64);
        float om2 = __shfl_xor(m2[s][r], d, 64);
        int oj = __shfl_xor(j1[s][r], d, 64);
        float hi;
        if (om1 < m1[s][r] || (om1 == m1[s][r] && oj < j1[s][r])) {
          hi = m1[s][r]; m1[s][r] = om1; j1[s][r] = oj;
        } else hi = om1;                 // equal-m1 merges force m2==m1 -> flagged
        m2[s][r] = fminf(m2[s][r], fminf(om2, hi));
      }
  }

  if (mrow == 0) {
#pragma unroll
    for (int s = 0; s < 2; ++s)
#pragma unroll
      for (int r = 0; r < 4; ++r) {
        int tok = w * 32 + s * 16 + quad * 4 + r;
        out_idx[t0 + tok] = (float)j1[s][r];
        if (m2[s][r] - m1[s][r] < TAU) {
          int pos = atomicAdd(amb_cnt, 1);
          if (pos < TOKENS) amb_list[pos] = t0 + tok;
        }
      }
  }
}

// ---------------- exact-np rescan: 4 tokens/block, 4 codes/thread ----------------
// Thread tid owns codes [4*tid, 4*tid+4) for ALL 4 tokens of the tile: each emb
// float4 is loaded once and reused 4x. Bitwise round-3/4 formula preserved:
// per-code ascending-c fmaf chain (x,y,z,w order, independent accumulator),
// ||z||^2 chain folded into the same ascending-c loop (identical order),
// d = fl(fl(A+B) - 2M). Argmin: in-thread strict-< over ascending codes,
// then associative lex-(d,j) tree reduce == first-index-among-ties.
#define RT 4
__global__ void __launch_bounds__(256)
k_rescan(const float* __restrict__ z, const float* __restrict__ emb,
         const float* __restrict__ en, const int* __restrict__ amb_cnt,
         const int* __restrict__ amb_list, float* __restrict__ out_idx) {
#pragma clang fp contract(off)
  __shared__ float zs[RT][256];
  __shared__ float m1s[RT][256];
  __shared__ int   jms[RT][256];
  int n = *amb_cnt;
  if (n > TOKENS) n = TOKENS;
  int ntiles = (n + RT - 1) / RT;
  int tid = threadIdx.x;
  int j0 = tid * 4;
  const float* e0 = emb + (size_t)j0 * ED;

  for (int tile = blockIdx.x; tile < ntiles; tile += gridDim.x) {
    __syncthreads();                       // protect zs/m1s reuse across tiles
#pragma unroll
    for (int it = 0; it < RT; ++it) {
      int i = tile * RT + it;
      int li = i < n ? i : n - 1;
      int t = amb_list[li];
      int b = t >> 15, s = t & 32767;
      zs[it][tid] = z[(size_t)b * ED * S + (size_t)tid * S + s];
    }
    __syncthreads();

    float A[RT];
    float a0[RT], a1[RT], a2[RT], a3[RT];
#pragma unroll
    for (int tk = 0; tk < RT; ++tk) {
      A[tk] = 0.f; a0[tk] = 0.f; a1[tk] = 0.f; a2[tk] = 0.f; a3[tk] = 0.f;
    }
    for (int c = 0; c < ED; c += 4) {
      float4 q0 = *(const float4*)(e0 + c);
      float4 q1 = *(const float4*)(e0 + 256 + c);
      float4 q2 = *(const float4*)(e0 + 512 + c);
      float4 q3 = *(const float4*)(e0 + 768 + c);
#pragma unroll
      for (int tk = 0; tk < RT; ++tk) {
        float4 zv = *(const float4*)(&zs[tk][c]);
        A[tk] = fmaf(zv.x, zv.x, A[tk]); A[tk] = fmaf(zv.y, zv.y, A[tk]);
        A[tk] = fmaf(zv.z, zv.z, A[tk]); A[tk] = fmaf(zv.w, zv.w, A[tk]);
        a0[tk] = fmaf(zv.x, q0.x, a0[tk]); a0[tk] = fmaf(zv.y, q0.y, a0[tk]);
        a0[tk] = fmaf(zv.z, q0.z, a0[tk]); a0[tk] = fmaf(zv.w, q0.w, a0[tk]);
        a1[tk] = fmaf(zv.x, q1.x, a1[tk]); a1[tk] = fmaf(zv.y, q1.y, a1[tk]);
        a1[tk] = fmaf(zv.z, q1.z, a1[tk]); a1[tk] = fmaf(zv.w, q1.w, a1[tk]);
        a2[tk] = fmaf(zv.x, q2.x, a2[tk]); a2[tk] = fmaf(zv.y, q2.y, a2[tk]);
        a2[tk] = fmaf(zv.z, q2.z, a2[tk]); a2[tk] = fmaf(zv.w, q2.w, a2[tk]);
        a3[tk] = fmaf(zv.x, q3.x, a3[tk]); a3[tk] = fmaf(zv.y, q3.y, a3[tk]);
        a3[tk] = fmaf(zv.w, q3.w, a3[tk]); a3[tk] = fmaf(zv.z, q3.z, a3[tk]);
      }
    }

    float e0n = en[j0 + 0], e1n = en[j0 + 1], e2n = en[j0 + 2], e3n = en[j0 + 3];
#pragma unroll
    for (int tk = 0; tk < RT; ++tk) {
      float d0 = (A[tk] + e0n) - 2.f * a0[tk];
      float d1 = (A[tk] + e1n) - 2.f * a1[tk];
      float d2 = (A[tk] + e2n) - 2.f * a2[tk];
      float d3 = (A[tk] + e3n) - 2.f * a3[tk];
      float bm = d0; int bi = j0;
      if (d1 < bm) { bm = d1; bi = j0 + 1; }
      if (d2 < bm) { bm = d2; bi = j0 + 2; }
      if (d3 < bm) { bm = d3; bi = j0 + 3; }
      m1s[tk][tid] = bm; jms[tk][tid] = bi;
    }
    __syncthreads();

    for (int off = 128; off > 0; off >>= 1) {
      if (tid < off) {
#pragma unroll
        for (int tk = 0; tk < RT; ++tk) {
          float dv = m1s[tk][tid + off]; int jv = jms[tk][tid + off];
          float dc = m1s[tk][tid];       int jc = jms[tk][tid];
          if (dv < dc || (dv == dc && jv < jc)) {
            m1s[tk][tid] = dv; jms[tk][tid] = jv;
          }
        }
      }
      __syncthreads();
    }

    if (tid < RT) {
      int i = tile * RT + tid;
      if (i < n) out_idx[amb_list[i]] = (float)jms[tid][0];
    }
  }
}

// ---------------- epilogue: z_q gather + loss + sampled ----------------
__global__ void __launch_bounds__(256)
k_epi(const float* __restrict__ z, const float* __restrict__ emb,
      const float* __restrict__ idxf, float* __restrict__ out_zq,
      float* __restrict__ out_samp, float* __restrict__ out_loss) {
  __shared__ float red[256];
  int tid = threadIdx.x;
  int lane = tid & 63;
  int w = tid >> 6;
  int t0 = blockIdx.x * 64;
  int b = t0 >> 15;
  int s0 = t0 & 32767;

  int jm = (int)idxf[t0 + lane];
  if (w == 0) out_samp[jm] = 1.0f;     // idx < 1024 -> always row 0

  const float* zb = z + ((size_t)b * ED * S) + s0;
  float* zqb = out_zq + ((size_t)b * ED * S) + s0;
  const float* erow = emb + (size_t)jm * ED;
  float lacc = 0.f;
  for (int cc = w; cc < ED; cc += 4) {
    float zq = erow[cc];
    float zv = zb[(size_t)cc * S + lane];
    float df = zq - zv;
    lacc = fmaf(df, df, lacc);
    zqb[(size_t)cc * S + lane] = zq;
  }
  red[tid] = lacc;
  __syncthreads();
  for (int off = 128; off > 0; off >>= 1) {
    if (tid < off) red[tid] += red[tid + off];
    __syncthreads();
  }
  if (tid == 0)
    atomicAdd(out_loss, red[0] * (1.2f / 16777216.0f));  // (1+BETA)*mean
}

// ---------------- codebook self-distance: LDS-tiled fp32 GEMM ----------------
__global__ void __launch_bounds__(256)
k_cd(const float* __restrict__ emb, const float* __restrict__ en,
     float* __restrict__ cd) {
  __shared__ float At[64 * 260];
  __shared__ float Bt[64 * 260];
  int bi = blockIdx.x >> 4, bj = blockIdx.x & 15;
  int tid = threadIdx.x;
  const float4* ev = (const float4*)emb;
  for (int idx = tid; idx < 64 * 64; idx += 256) {
    int row = idx >> 6, c4 = idx & 63;
    *(float4*)(&At[row * 260 + c4 * 4]) = ev[(size_t)(bi * 64 + row) * 64 + c4];
    *(float4*)(&Bt[row * 260 + c4 * 4]) = ev[(size_t)(bj * 64 + row) * 64 + c4];
  }
  __syncthreads();
  int ti = tid & 15, tj = tid >> 4;
  float acc[4][4] = {};
  for (int c = 0; c < ED; c += 4) {
    float4 a[4], bq[4];
#pragma unroll
    for (int p = 0; p < 4; ++p) a[p] = *(const float4*)(&At[(ti * 4 + p) * 260 + c]);
#pragma unroll
    for (int q = 0; q < 4; ++q) bq[q] = *(const float4*)(&Bt[(tj * 4 + q) * 260 + c]);
#pragma unroll
    for (int p = 0; p < 4; ++p)
#pragma unroll
      for (int q = 0; q < 4; ++q) {
        acc[p][q] = fmaf(a[p].x, bq[q].x, acc[p][q]);
        acc[p][q] = fmaf(a[p].y, bq[q].y, acc[p][q]);
        acc[p][q] = fmaf(a[p].z, bq[q].z, acc[p][q]);
        acc[p][q] = fmaf(a[p].w, bq[q].w, acc[p][q]);
      }
  }
#pragma unroll
  for (int p = 0; p < 4; ++p)
#pragma unroll
    for (int q = 0; q < 4; ++q) {
      int i = bi * 64 + ti * 4 + p;
      int j = bj * 64 + tj * 4 + q;
      cd[(size_t)i * NE + j] = (en[i] + en[j]) - 2.f * acc[p][q];
    }
}

// ---------------- per-column 2nd smallest -> mean ----------------
// 64 blocks x 16 cols; 16 row-chunks of 64 per column, LDS merge.
__global__ void __launch_bounds__(256)
k_colstats(const float* __restrict__ cd, float* __restrict__ out_md) {
  int tid = threadIdx.x;
  int j = blockIdx.x * 16 + (tid & 15);
  int chunk = tid >> 4;
  float m1 = 3.4e38f, m2 = 3.4e38f;
  int r0 = chunk * 64;
  for (int r = r0; r < r0 + 64; ++r) {
    float v = cd[(size_t)r * NE + j];
    if (v < m1) { m2 = m1; m1 = v; }
    else if (v < m2) { m2 = v; }
  }
  __shared__ float s1[256], s2[256];
  s1[tid] = m1; s2[tid] = m2;
  __syncthreads();
  if (chunk == 0) {
    for (int cc = 1; cc < 16; ++cc) {
      float n1 = s1[cc * 16 + tid], n2 = s2[cc * 16 + tid];
      float lo = fminf(m1, n1);
      float hi = fmaxf(m1, n1);
      m2 = fminf(hi, fminf(m2, n2));
      m1 = lo;
    }
    atomicAdd(out_md, m2 * (1.0f / 1024.0f));
  }
}

// ---------------- per-row variance (ddof=1) -> mean ----------------
__global__ void k_var(const float* __restrict__ cd, float* __restrict__ out_mv) {
  int i = blockIdx.x;
  int tid = threadIdx.x;
  const float* row = cd + (size_t)i * NE;
  __shared__ float red[256];
  float s = row[tid] + row[tid + 256] + row[tid + 512] + row[tid + 768];
  red[tid] = s;
  __syncthreads();
  for (int off = 128; off > 0; off >>= 1) {
    if (tid < off) red[tid] += red[tid + off];
    __syncthreads();
  }
  float mean = red[0] * (1.0f / 1024.0f);
  __syncthreads();
  float d0 = row[tid] - mean, d1 = row[tid + 256] - mean,
        d2 = row[tid + 512] - mean, d3 = row[tid + 768] - mean;
  red[tid] = d0 * d0 + d1 * d1 + d2 * d2 + d3 * d3;
  __syncthreads();
  for (int off = 128; off > 0; off >>= 1) {
    if (tid < off) red[tid] += red[tid + off];
    __syncthreads();
  }
  if (tid == 0)
    atomicAdd(out_mv, red[0] * (1.0f / 1023.0f) * (1.0f / 1024.0f));
}

extern "C" void kernel_launch(void* const* d_in, const int* in_sizes, int n_in,
                              void* d_out, int out_size, void* d_ws, size_t ws_size,
                              hipStream_t stream) {
  const float* z   = (const float*)d_in[0];
  const float* emb = (const float*)d_in[1];
  float* out = (float*)d_out;

  float* cd = (float*)d_ws;                       // 4 MiB
  float* en = cd + (size_t)NE * NE;               // 4 KiB
  _Float16* embf = (_Float16*)(en + NE);          // 512 KiB fragment-ordered fp16
  int* amb_cnt = (int*)(embf + (size_t)NE * ED);
  int* amb_list = amb_cnt + 16;                   // up to TOKENS ints

  hipMemsetAsync(out + OFF_LOSS, 0,
                 (size_t)(out_size - OFF_LOSS) * sizeof(float), stream);
  hipMemsetAsync(amb_cnt, 0, sizeof(int), stream);

  k_enorm<<<NE / 256, 256, 0, stream>>>(emb, en);
  k_cvt<<<64, 512, 0, stream>>>(emb, embf);
  k_filter<<<TOKENS / 128, 256, 0, stream>>>(z, embf, en, out + OFF_IDX,
                                             amb_cnt, amb_list);
  k_rescan<<<2048, 256, 0, stream>>>(z, emb, en, amb_cnt, amb_list, out + OFF_IDX);
  k_epi<<<TOKENS / 64, 256, 0, stream>>>(z, emb, out + OFF_IDX,
                                         out, out + OFF_SAMP, out + OFF_LOSS);
  k_cd<<<256, 256, 0, stream>>>(emb, en, cd);
  k_colstats<<<64, 256, 0, stream>>>(cd, out + OFF_MD);
  k_var<<<NE, 256, 0, stream>>>(cd, out + OFF_MV);
}

// Round 3
// 478.843 us; speedup vs baseline: 1.0836x; 1.0622x over previous
//
#include <hip/hip_runtime.h>
#include <stdint.h>

#define NE   1024
#define ED   256
#define NB   2
#define S    32768            // 32*32*32
#define TOKENS (NB*S)         // 65536

#define OFF_LOSS 16777216
#define OFF_IDX  16777217
#define OFF_SAMP 16842753
#define OFF_MD   16844801
#define OFF_MV   16844802

#define TAU 2.5e-4f           // fp16-filter ambiguity margin (~6 sigma of 3e-5 err)
#define ZCAP_MAX 16384        // max compacted z rows (16.8 MiB)

typedef _Float16 half8 __attribute__((ext_vector_type(8)));
typedef float floatx4 __attribute__((ext_vector_type(4)));

// ---------------- codebook norms: bitwise numpy pairwise sum ----------------
__global__ void k_enorm(const float* __restrict__ emb, float* __restrict__ en) {
#pragma clang fp contract(off)
  int j = blockIdx.x * 256 + threadIdx.x;
  const float* e = emb + (size_t)j * ED;
  float halves[2];
  for (int h = 0; h < 2; ++h) {
    const float* a = e + h * 128;
    float r[8];
    for (int k = 0; k < 8; ++k) r[k] = a[k] * a[k];
    for (int i = 8; i < 128; i += 8)
      for (int k = 0; k < 8; ++k) r[k] += a[i + k] * a[i + k];
    halves[h] = ((r[0] + r[1]) + (r[2] + r[3])) + ((r[4] + r[5]) + (r[6] + r[7]));
  }
  en[j] = halves[0] + halves[1];
}

// ---------------- emb -> fragment-ordered fp16 ----------------
__global__ void k_cvt(const float* __restrict__ emb, _Float16* __restrict__ embf) {
  int g = blockIdx.x * 512 + threadIdx.x;   // 64 blocks x 512 = 32768
  int lane = g & 63;
  int ks = (g >> 6) & 7;
  int nt = g >> 9;
  int n = nt * 16 + (lane & 15);
  int k0 = ks * 32 + (lane >> 4) * 8;
  const float* src = emb + (size_t)n * ED + k0;
  half8 v;
#pragma unroll
  for (int j = 0; j < 8; ++j) v[j] = (_Float16)src[j];
  *(half8*)(embf + ((size_t)((nt * 8 + ks) * 64 + lane)) * 8) = v;
}

// ---------------- MFMA filter: approx argmin + top-2 ambiguity ----------------
// 128 tokens/block, 256 thr = 4 waves; wave w owns tokens [w*32, w*32+32)
// (2 m-stripes of 16). Sweeps all 1024 codes via 64 n-tiles of 16x16x32 mfma.
// NEW: collects this block's ambiguous tokens, takes one global base, and
// writes their exact fp32 z vectors COMPACTED into zamb (coalesced 1KB rows).
// The per-channel re-reads hit L2 (lines staged microseconds earlier).
__global__ void __launch_bounds__(256)
k_filter(const float* __restrict__ z, const _Float16* __restrict__ embf,
         const float* __restrict__ en, float* __restrict__ out_idx,
         int* __restrict__ amb_cnt, int* __restrict__ amb_list,
         float* __restrict__ zamb, int zcap) {
  __shared__ _Float16 zA[128 * 264];   // [tok][c], stride 264 -> 2-way banks
  __shared__ float en_s[NE];
  __shared__ int loc_cnt, loc_base;
  __shared__ int loc_tok[128];

  int tid = threadIdx.x;
  int lane = tid & 63;
  int w = tid >> 6;
  int mrow = lane & 15;
  int quad = lane >> 4;
  int t0 = blockIdx.x * 128;
  int b = t0 >> 15;                    // 32768 % 128 == 0: no straddle
  int s0 = t0 & 32767;

  if (tid == 0) loc_cnt = 0;
  for (int i = tid; i < NE; i += 256) en_s[i] = en[i];

  {  // stage z tile -> fp16 LDS (coalesced along s, rne convert)
    int tok = tid & 127;
    int ch = tid >> 7;
    const float* zb = z + (size_t)b * ED * S + s0 + tok;
    for (int it = 0; it < 16; ++it) {
      int c0 = ch * 8 + it * 16;
      half8 v;
#pragma unroll
      for (int j = 0; j < 8; ++j) v[j] = (_Float16)zb[(size_t)(c0 + j) * S];
      *(half8*)(&zA[tok * 264 + c0]) = v;
    }
  }
  __syncthreads();

  // A-frags register-resident: af[stripe][kstep]
  half8 af[2][8];
#pragma unroll
  for (int s = 0; s < 2; ++s)
#pragma unroll
    for (int ks = 0; ks < 8; ++ks)
      af[s][ks] = *(const half8*)(&zA[(w * 32 + s * 16 + mrow) * 264 + ks * 32 + quad * 8]);

  float m1[2][4], m2[2][4];
  int j1[2][4];
#pragma unroll
  for (int s = 0; s < 2; ++s)
#pragma unroll
    for (int r = 0; r < 4; ++r) { m1[s][r] = 3.4e38f; m2[s][r] = 3.4e38f; j1[s][r] = 0; }

  for (int nt = 0; nt < 64; ++nt) {
    floatx4 acc0 = {0.f, 0.f, 0.f, 0.f}, acc1 = {0.f, 0.f, 0.f, 0.f};
    const half8* pb = (const half8*)(embf + ((size_t)(nt * 8) * 64 + lane) * 8);
#pragma unroll
    for (int ks = 0; ks < 8; ++ks) {
      half8 bf = pb[ks * 64];          // coalesced 16B/lane from L2
      acc0 = __builtin_amdgcn_mfma_f32_16x16x32_f16(af[0][ks], bf, acc0, 0, 0, 0);
      acc1 = __builtin_amdgcn_mfma_f32_16x16x32_f16(af[1][ks], bf, acc1, 0, 0, 0);
    }
    int j = nt * 16 + mrow;
    float Bj = en_s[j];                // ||z||^2 constant per token -> dropped
#pragma unroll
    for (int r = 0; r < 4; ++r) {
      float d0 = Bj - 2.f * acc0[r];
      float d1 = Bj - 2.f * acc1[r];
      if (d0 < m1[0][r]) { m2[0][r] = m1[0][r]; m1[0][r] = d0; j1[0][r] = j; }
      else if (d0 < m2[0][r]) m2[0][r] = d0;
      if (d1 < m1[1][r]) { m2[1][r] = m1[1][r]; m1[1][r] = d1; j1[1][r] = j; }
      else if (d1 < m2[1][r]) m2[1][r] = d1;
    }
  }

  // merge across the 16 lanes of each quad (same tokens, different codes)
#pragma unroll
  for (int d = 1; d < 16; d <<= 1) {
#pragma unroll
    for (int s = 0; s < 2; ++s)
#pragma unroll
      for (int r = 0; r < 4; ++r) {
        float om1 = __shfl_xor(m1[s][r], d, 64);
        float om2 = __shfl_xor(m2[s][r], d, 64);
        int oj = __shfl_xor(j1[s][r], d, 64);
        float hi;
        if (om1 < m1[s][r] || (om1 == m1[s][r] && oj < j1[s][r])) {
          hi = m1[s][r]; m1[s][r] = om1; j1[s][r] = oj;
        } else hi = om1;                 // equal-m1 merges force m2==m1 -> flagged
        m2[s][r] = fminf(m2[s][r], fminf(om2, hi));
      }
  }

  if (mrow == 0) {
#pragma unroll
    for (int s = 0; s < 2; ++s)
#pragma unroll
      for (int r = 0; r < 4; ++r) {
        int tok = w * 32 + s * 16 + quad * 4 + r;
        out_idx[t0 + tok] = (float)j1[s][r];
        if (m2[s][r] - m1[s][r] < TAU) {
          int p = atomicAdd(&loc_cnt, 1);
          loc_tok[p] = tok;
        }
      }
  }
  __syncthreads();
  if (tid == 0) loc_base = (loc_cnt > 0) ? atomicAdd(amb_cnt, loc_cnt) : 0;
  __syncthreads();

  // compact copy-out: one coalesced 1KB zamb row per ambiguous token.
  // Source loads are strided but L2-hot (just staged by this block).
  int cnt = loc_cnt;
  int base = loc_base;
  const float* zcol = z + (size_t)b * ED * S + s0;
  for (int k = 0; k < cnt; ++k) {
    int lt = loc_tok[k];
    int gpos = base + k;
    if (gpos < TOKENS) {
      if (tid == 0) amb_list[gpos] = t0 + lt;
      if (gpos < zcap)
        zamb[(size_t)gpos * ED + tid] = zcol[(size_t)tid * S + lt];
    }
  }
}

// ---------------- exact-np rescan: 4 tokens/block, 4 codes/thread ----------------
// Thread tid owns codes [4*tid, 4*tid+4) for ALL 4 tokens of the tile: each emb
// float4 is loaded once and reused 4x. z vectors come from the COMPACTED zamb
// buffer (contiguous 1KB rows, coalesced; no channel-serialized stride-S gather).
// Rows >= zcap (workspace overflow, normally never) fall back to strided z.
// Bitwise round-3/4 formula preserved: per-code ascending-c fmaf chain
// (x,y,z,w order, independent accumulator), ||z||^2 chain folded into the same
// ascending-c loop, d = fl(fl(A+B) - 2M). Argmin: in-thread strict-< over
// ascending codes, then associative lex-(d,j) tree reduce == first-index.
#define RT 4
__global__ void __launch_bounds__(256)
k_rescan(const float* __restrict__ z, const float* __restrict__ emb,
         const float* __restrict__ en, const int* __restrict__ amb_cnt,
         const int* __restrict__ amb_list, const float* __restrict__ zamb,
         int zcap, float* __restrict__ out_idx) {
#pragma clang fp contract(off)
  __shared__ float zs[RT][256];
  __shared__ float m1s[RT][256];
  __shared__ int   jms[RT][256];
  int n = *amb_cnt;
  if (n > TOKENS) n = TOKENS;
  int ntiles = (n + RT - 1) / RT;
  int tid = threadIdx.x;
  int j0 = tid * 4;
  const float* e0 = emb + (size_t)j0 * ED;

  for (int tile = blockIdx.x; tile < ntiles; tile += gridDim.x) {
    __syncthreads();                       // protect zs/m1s reuse across tiles
#pragma unroll
    for (int it = 0; it < RT; ++it) {
      int i = tile * RT + it;
      int li = i < n ? i : n - 1;
      if (li < zcap) {
        zs[it][tid] = zamb[(size_t)li * ED + tid];       // coalesced row
      } else {
        int t = amb_list[li];
        int b = t >> 15, s = t & 32767;
        zs[it][tid] = z[(size_t)b * ED * S + (size_t)tid * S + s];
      }
    }
    __syncthreads();

    float A[RT];
    float a0[RT], a1[RT], a2[RT], a3[RT];
#pragma unroll
    for (int tk = 0; tk < RT; ++tk) {
      A[tk] = 0.f; a0[tk] = 0.f; a1[tk] = 0.f; a2[tk] = 0.f; a3[tk] = 0.f;
    }
    for (int c = 0; c < ED; c += 4) {
      float4 q0 = *(const float4*)(e0 + c);
      float4 q1 = *(const float4*)(e0 + 256 + c);
      float4 q2 = *(const float4*)(e0 + 512 + c);
      float4 q3 = *(const float4*)(e0 + 768 + c);
#pragma unroll
      for (int tk = 0; tk < RT; ++tk) {
        float4 zv = *(const float4*)(&zs[tk][c]);
        A[tk] = fmaf(zv.x, zv.x, A[tk]); A[tk] = fmaf(zv.y, zv.y, A[tk]);
        A[tk] = fmaf(zv.z, zv.z, A[tk]); A[tk] = fmaf(zv.w, zv.w, A[tk]);
        a0[tk] = fmaf(zv.x, q0.x, a0[tk]); a0[tk] = fmaf(zv.y, q0.y, a0[tk]);
        a0[tk] = fmaf(zv.z, q0.z, a0[tk]); a0[tk] = fmaf(zv.w, q0.w, a0[tk]);
        a1[tk] = fmaf(zv.x, q1.x, a1[tk]); a1[tk] = fmaf(zv.y, q1.y, a1[tk]);
        a1[tk] = fmaf(zv.z, q1.z, a1[tk]); a1[tk] = fmaf(zv.w, q1.w, a1[tk]);
        a2[tk] = fmaf(zv.x, q2.x, a2[tk]); a2[tk] = fmaf(zv.y, q2.y, a2[tk]);
        a2[tk] = fmaf(zv.z, q2.z, a2[tk]); a2[tk] = fmaf(zv.w, q2.w, a2[tk]);
        a3[tk] = fmaf(zv.x, q3.x, a3[tk]); a3[tk] = fmaf(zv.y, q3.y, a3[tk]);
        a3[tk] = fmaf(zv.z, q3.z, a3[tk]); a3[tk] = fmaf(zv.w, q3.w, a3[tk]);
      }
    }

    float e0n = en[j0 + 0], e1n = en[j0 + 1], e2n = en[j0 + 2], e3n = en[j0 + 3];
#pragma unroll
    for (int tk = 0; tk < RT; ++tk) {
      float d0 = (A[tk] + e0n) - 2.f * a0[tk];
      float d1 = (A[tk] + e1n) - 2.f * a1[tk];
      float d2 = (A[tk] + e2n) - 2.f * a2[tk];
      float d3 = (A[tk] + e3n) - 2.f * a3[tk];
      float bm = d0; int bi = j0;
      if (d1 < bm) { bm = d1; bi = j0 + 1; }
      if (d2 < bm) { bm = d2; bi = j0 + 2; }
      if (d3 < bm) { bm = d3; bi = j0 + 3; }
      m1s[tk][tid] = bm; jms[tk][tid] = bi;
    }
    __syncthreads();

    for (int off = 128; off > 0; off >>= 1) {
      if (tid < off) {
#pragma unroll
        for (int tk = 0; tk < RT; ++tk) {
          float dv = m1s[tk][tid + off]; int jv = jms[tk][tid + off];
          float dc = m1s[tk][tid];       int jc = jms[tk][tid];
          if (dv < dc || (dv == dc && jv < jc)) {
            m1s[tk][tid] = dv; jms[tk][tid] = jv;
          }
        }
      }
      __syncthreads();
    }

    if (tid < RT) {
      int i = tile * RT + tid;
      if (i < n) out_idx[amb_list[i]] = (float)jms[tid][0];
    }
  }
}

// ---------------- epilogue: z_q gather + loss + sampled ----------------
__global__ void __launch_bounds__(256)
k_epi(const float* __restrict__ z, const float* __restrict__ emb,
      const float* __restrict__ idxf, float* __restrict__ out_zq,
      float* __restrict__ out_samp, float* __restrict__ out_loss) {
  __shared__ float red[256];
  int tid = threadIdx.x;
  int lane = tid & 63;
  int w = tid >> 6;
  int t0 = blockIdx.x * 64;
  int b = t0 >> 15;
  int s0 = t0 & 32767;

  int jm = (int)idxf[t0 + lane];
  if (w == 0) out_samp[jm] = 1.0f;     // idx < 1024 -> always row 0

  const float* zb = z + ((size_t)b * ED * S) + s0;
  float* zqb = out_zq + ((size_t)b * ED * S) + s0;
  const float* erow = emb + (size_t)jm * ED;
  float lacc = 0.f;
  for (int cc = w; cc < ED; cc += 4) {
    float zq = erow[cc];
    float zv = zb[(size_t)cc * S + lane];
    float df = zq - zv;
    lacc = fmaf(df, df, lacc);
    zqb[(size_t)cc * S + lane] = zq;
  }
  red[tid] = lacc;
  __syncthreads();
  for (int off = 128; off > 0; off >>= 1) {
    if (tid < off) red[tid] += red[tid + off];
    __syncthreads();
  }
  if (tid == 0)
    atomicAdd(out_loss, red[0] * (1.2f / 16777216.0f));  // (1+BETA)*mean
}

// ---------------- codebook self-distance: LDS-tiled fp32 GEMM ----------------
__global__ void __launch_bounds__(256)
k_cd(const float* __restrict__ emb, const float* __restrict__ en,
     float* __restrict__ cd) {
  __shared__ float At[64 * 260];
  __shared__ float Bt[64 * 260];
  int bi = blockIdx.x >> 4, bj = blockIdx.x & 15;
  int tid = threadIdx.x;
  const float4* ev = (const float4*)emb;
  for (int idx = tid; idx < 64 * 64; idx += 256) {
    int row = idx >> 6, c4 = idx & 63;
    *(float4*)(&At[row * 260 + c4 * 4]) = ev[(size_t)(bi * 64 + row) * 64 + c4];
    *(float4*)(&Bt[row * 260 + c4 * 4]) = ev[(size_t)(bj * 64 + row) * 64 + c4];
  }
  __syncthreads();
  int ti = tid & 15, tj = tid >> 4;
  float acc[4][4] = {};
  for (int c = 0; c < ED; c += 4) {
    float4 a[4], bq[4];
#pragma unroll
    for (int p = 0; p < 4; ++p) a[p] = *(const float4*)(&At[(ti * 4 + p) * 260 + c]);
#pragma unroll
    for (int q = 0; q < 4; ++q) bq[q] = *(const float4*)(&Bt[(tj * 4 + q) * 260 + c]);
#pragma unroll
    for (int p = 0; p < 4; ++p)
#pragma unroll
      for (int q = 0; q < 4; ++q) {
        acc[p][q] = fmaf(a[p].x, bq[q].x, acc[p][q]);
        acc[p][q] = fmaf(a[p].y, bq[q].y, acc[p][q]);
        acc[p][q] = fmaf(a[p].z, bq[q].z, acc[p][q]);
        acc[p][q] = fmaf(a[p].w, bq[q].w, acc[p][q]);
      }
  }
#pragma unroll
  for (int p = 0; p < 4; ++p)
#pragma unroll
    for (int q = 0; q < 4; ++q) {
      int i = bi * 64 + ti * 4 + p;
      int j = bj * 64 + tj * 4 + q;
      cd[(size_t)i * NE + j] = (en[i] + en[j]) - 2.f * acc[p][q];
    }
}

// ---------------- per-column 2nd smallest -> mean ----------------
// 64 blocks x 16 cols; 16 row-chunks of 64 per column, LDS merge.
__global__ void __launch_bounds__(256)
k_colstats(const float* __restrict__ cd, float* __restrict__ out_md) {
  int tid = threadIdx.x;
  int j = blockIdx.x * 16 + (tid & 15);
  int chunk = tid >> 4;
  float m1 = 3.4e38f, m2 = 3.4e38f;
  int r0 = chunk * 64;
  for (int r = r0; r < r0 + 64; ++r) {
    float v = cd[(size_t)r * NE + j];
    if (v < m1) { m2 = m1; m1 = v; }
    else if (v < m2) { m2 = v; }
  }
  __shared__ float s1[256], s2[256];
  s1[tid] = m1; s2[tid] = m2;
  __syncthreads();
  if (chunk == 0) {
    for (int cc = 1; cc < 16; ++cc) {
      float n1 = s1[cc * 16 + tid], n2 = s2[cc * 16 + tid];
      float lo = fminf(m1, n1);
      float hi = fmaxf(m1, n1);
      m2 = fminf(hi, fminf(m2, n2));
      m1 = lo;
    }
    atomicAdd(out_md, m2 * (1.0f / 1024.0f));
  }
}

// ---------------- per-row variance (ddof=1) -> mean ----------------
__global__ void k_var(const float* __restrict__ cd, float* __restrict__ out_mv) {
  int i = blockIdx.x;
  int tid = threadIdx.x;
  const float* row = cd + (size_t)i * NE;
  __shared__ float red[256];
  float s = row[tid] + row[tid + 256] + row[tid + 512] + row[tid + 768];
  red[tid] = s;
  __syncthreads();
  for (int off = 128; off > 0; off >>= 1) {
    if (tid < off) red[tid] += red[tid + off];
    __syncthreads();
  }
  float mean = red[0] * (1.0f / 1024.0f);
  __syncthreads();
  float d0 = row[tid] - mean, d1 = row[tid + 256] - mean,
        d2 = row[tid + 512] - mean, d3 = row[tid + 768] - mean;
  red[tid] = d0 * d0 + d1 * d1 + d2 * d2 + d3 * d3;
  __syncthreads();
  for (int off = 128; off > 0; off >>= 1) {
    if (tid < off) red[tid] += red[tid + off];
    __syncthreads();
  }
  if (tid == 0)
    atomicAdd(out_mv, red[0] * (1.0f / 1023.0f) * (1.0f / 1024.0f));
}

extern "C" void kernel_launch(void* const* d_in, const int* in_sizes, int n_in,
                              void* d_out, int out_size, void* d_ws, size_t ws_size,
                              hipStream_t stream) {
  const float* z   = (const float*)d_in[0];
  const float* emb = (const float*)d_in[1];
  float* out = (float*)d_out;

  float* cd = (float*)d_ws;                       // 4 MiB
  float* en = cd + (size_t)NE * NE;               // 4 KiB
  _Float16* embf = (_Float16*)(en + NE);          // 512 KiB fragment-ordered fp16
  int* amb_cnt = (int*)(embf + (size_t)NE * ED);
  int* amb_list = amb_cnt + 16;                   // TOKENS ints (256 KiB)
  float* zamb = (float*)(amb_list + TOKENS);      // compacted z rows (1KB each)

  // zcap from actual workspace size: graceful fallback if ws is small.
  size_t base_bytes = (size_t)((char*)zamb - (char*)d_ws);
  int zcap = 0;
  if (ws_size > base_bytes) {
    size_t rows = (ws_size - base_bytes) / ((size_t)ED * sizeof(float));
    zcap = rows > (size_t)ZCAP_MAX ? ZCAP_MAX : (int)rows;
  }

  hipMemsetAsync(out + OFF_LOSS, 0,
                 (size_t)(out_size - OFF_LOSS) * sizeof(float), stream);
  hipMemsetAsync(amb_cnt, 0, sizeof(int), stream);

  k_enorm<<<NE / 256, 256, 0, stream>>>(emb, en);
  k_cvt<<<64, 512, 0, stream>>>(emb, embf);
  k_filter<<<TOKENS / 128, 256, 0, stream>>>(z, embf, en, out + OFF_IDX,
                                             amb_cnt, amb_list, zamb, zcap);
  k_rescan<<<2048, 256, 0, stream>>>(z, emb, en, amb_cnt, amb_list,
                                     zamb, zcap, out + OFF_IDX);
  k_epi<<<TOKENS / 64, 256, 0, stream>>>(z, emb, out + OFF_IDX,
                                         out, out + OFF_SAMP, out + OFF_LOSS);
  k_cd<<<256, 256, 0, stream>>>(emb, en, cd);
  k_colstats<<<64, 256, 0, stream>>>(cd, out + OFF_MD);
  k_var<<<NE, 256, 0, stream>>>(cd, out + OFF_MV);
}

// Round 4
// 395.384 us; speedup vs baseline: 1.3123x; 1.2111x over previous
//
#include <hip/hip_runtime.h>
#include <stdint.h>

#define NE   1024
#define ED   256
#define NB   2
#define S    32768            // 32*32*32
#define TOKENS (NB*S)         // 65536

#define OFF_LOSS 16777216
#define OFF_IDX  16777217
#define OFF_SAMP 16842753
#define OFF_MD   16844801
#define OFF_MV   16844802

#define TAU 2.5e-4f           // fp16-filter ambiguity margin (~6 sigma of 3e-5 err)
#define ZCAP_MAX 16384        // max compacted z rows (16.8 MiB)

typedef _Float16 half8 __attribute__((ext_vector_type(8)));
typedef float floatx4 __attribute__((ext_vector_type(4)));

// ---------------- codebook norms: bitwise numpy pairwise sum ----------------
__global__ void k_enorm(const float* __restrict__ emb, float* __restrict__ en) {
#pragma clang fp contract(off)
  int j = blockIdx.x * 256 + threadIdx.x;
  const float* e = emb + (size_t)j * ED;
  float halves[2];
  for (int h = 0; h < 2; ++h) {
    const float* a = e + h * 128;
    float r[8];
    for (int k = 0; k < 8; ++k) r[k] = a[k] * a[k];
    for (int i = 8; i < 128; i += 8)
      for (int k = 0; k < 8; ++k) r[k] += a[i + k] * a[i + k];
    halves[h] = ((r[0] + r[1]) + (r[2] + r[3])) + ((r[4] + r[5]) + (r[6] + r[7]));
  }
  en[j] = halves[0] + halves[1];
}

// ---------------- emb -> fragment-ordered fp16 ----------------
__global__ void k_cvt(const float* __restrict__ emb, _Float16* __restrict__ embf) {
  int g = blockIdx.x * 512 + threadIdx.x;   // 64 blocks x 512 = 32768
  int lane = g & 63;
  int ks = (g >> 6) & 7;
  int nt = g >> 9;
  int n = nt * 16 + (lane & 15);
  int k0 = ks * 32 + (lane >> 4) * 8;
  const float* src = emb + (size_t)n * ED + k0;
  half8 v;
#pragma unroll
  for (int j = 0; j < 8; ++j) v[j] = (_Float16)src[j];
  *(half8*)(embf + ((size_t)((nt * 8 + ks) * 64 + lane)) * 8) = v;
}

// ---------------- emb -> transposed fp32 embT[c][j] (for coalesced rescan) ----
__global__ void __launch_bounds__(256)
k_tr(const float* __restrict__ emb, float* __restrict__ embT) {
  __shared__ float t[32][33];
  int bj = blockIdx.x >> 3;            // 0..31: code tile
  int bc = blockIdx.x & 7;             // 0..7 : channel tile
  int tx = threadIdx.x & 31, ty = threadIdx.x >> 5;
  int j0 = bj * 32, c0 = bc * 32;
#pragma unroll
  for (int k = 0; k < 4; ++k)
    t[ty + 8 * k][tx] = emb[(size_t)(j0 + ty + 8 * k) * ED + c0 + tx];
  __syncthreads();
#pragma unroll
  for (int k = 0; k < 4; ++k)
    embT[(size_t)(c0 + ty + 8 * k) * NE + j0 + tx] = t[tx][ty + 8 * k];
}

// ---------------- MFMA filter: approx argmin + top-2 ambiguity ----------------
// 128 tokens/block, 256 thr = 4 waves; wave w owns tokens [w*32, w*32+32)
// (2 m-stripes of 16). Sweeps all 1024 codes via 64 n-tiles of 16x16x32 mfma.
// Collects this block's ambiguous tokens, takes one global base, and writes
// their exact fp32 z vectors COMPACTED into zamb (coalesced 1KB rows).
__global__ void __launch_bounds__(256)
k_filter(const float* __restrict__ z, const _Float16* __restrict__ embf,
         const float* __restrict__ en, float* __restrict__ out_idx,
         int* __restrict__ amb_cnt, int* __restrict__ amb_list,
         float* __restrict__ zamb, int zcap) {
  __shared__ _Float16 zA[128 * 264];   // [tok][c], stride 264 -> 2-way banks
  __shared__ float en_s[NE];
  __shared__ int loc_cnt, loc_base;
  __shared__ int loc_tok[128];

  int tid = threadIdx.x;
  int lane = tid & 63;
  int w = tid >> 6;
  int mrow = lane & 15;
  int quad = lane >> 4;
  int t0 = blockIdx.x * 128;
  int b = t0 >> 15;                    // 32768 % 128 == 0: no straddle
  int s0 = t0 & 32767;

  if (tid == 0) loc_cnt = 0;
  for (int i = tid; i < NE; i += 256) en_s[i] = en[i];

  {  // stage z tile -> fp16 LDS (coalesced along s, rne convert)
    int tok = tid & 127;
    int ch = tid >> 7;
    const float* zb = z + (size_t)b * ED * S + s0 + tok;
    for (int it = 0; it < 16; ++it) {
      int c0 = ch * 8 + it * 16;
      half8 v;
#pragma unroll
      for (int j = 0; j < 8; ++j) v[j] = (_Float16)zb[(size_t)(c0 + j) * S];
      *(half8*)(&zA[tok * 264 + c0]) = v;
    }
  }
  __syncthreads();

  // A-frags register-resident: af[stripe][kstep]
  half8 af[2][8];
#pragma unroll
  for (int s = 0; s < 2; ++s)
#pragma unroll
    for (int ks = 0; ks < 8; ++ks)
      af[s][ks] = *(const half8*)(&zA[(w * 32 + s * 16 + mrow) * 264 + ks * 32 + quad * 8]);

  float m1[2][4], m2[2][4];
  int j1[2][4];
#pragma unroll
  for (int s = 0; s < 2; ++s)
#pragma unroll
    for (int r = 0; r < 4; ++r) { m1[s][r] = 3.4e38f; m2[s][r] = 3.4e38f; j1[s][r] = 0; }

  for (int nt = 0; nt < 64; ++nt) {
    floatx4 acc0 = {0.f, 0.f, 0.f, 0.f}, acc1 = {0.f, 0.f, 0.f, 0.f};
    const half8* pb = (const half8*)(embf + ((size_t)(nt * 8) * 64 + lane) * 8);
#pragma unroll
    for (int ks = 0; ks < 8; ++ks) {
      half8 bf = pb[ks * 64];          // coalesced 16B/lane from L2
      acc0 = __builtin_amdgcn_mfma_f32_16x16x32_f16(af[0][ks], bf, acc0, 0, 0, 0);
      acc1 = __builtin_amdgcn_mfma_f32_16x16x32_f16(af[1][ks], bf, acc1, 0, 0, 0);
    }
    int j = nt * 16 + mrow;
    float Bj = en_s[j];                // ||z||^2 constant per token -> dropped
#pragma unroll
    for (int r = 0; r < 4; ++r) {
      float d0 = Bj - 2.f * acc0[r];
      float d1 = Bj - 2.f * acc1[r];
      if (d0 < m1[0][r]) { m2[0][r] = m1[0][r]; m1[0][r] = d0; j1[0][r] = j; }
      else if (d0 < m2[0][r]) m2[0][r] = d0;
      if (d1 < m1[1][r]) { m2[1][r] = m1[1][r]; m1[1][r] = d1; j1[1][r] = j; }
      else if (d1 < m2[1][r]) m2[1][r] = d1;
    }
  }

  // merge across the 16 lanes of each quad (same tokens, different codes)
#pragma unroll
  for (int d = 1; d < 16; d <<= 1) {
#pragma unroll
    for (int s = 0; s < 2; ++s)
#pragma unroll
      for (int r = 0; r < 4; ++r) {
        float om1 = __shfl_xor(m1[s][r], d, 64);
        float om2 = __shfl_xor(m2[s][r], d, 64);
        int oj = __shfl_xor(j1[s][r], d, 64);
        float hi;
        if (om1 < m1[s][r] || (om1 == m1[s][r] && oj < j1[s][r])) {
          hi = m1[s][r]; m1[s][r] = om1; j1[s][r] = oj;
        } else hi = om1;                 // equal-m1 merges force m2==m1 -> flagged
        m2[s][r] = fminf(m2[s][r], fminf(om2, hi));
      }
  }

  if (mrow == 0) {
#pragma unroll
    for (int s = 0; s < 2; ++s)
#pragma unroll
      for (int r = 0; r < 4; ++r) {
        int tok = w * 32 + s * 16 + quad * 4 + r;
        out_idx[t0 + tok] = (float)j1[s][r];
        if (m2[s][r] - m1[s][r] < TAU) {
          int p = atomicAdd(&loc_cnt, 1);
          loc_tok[p] = tok;
        }
      }
  }
  __syncthreads();
  if (tid == 0) loc_base = (loc_cnt > 0) ? atomicAdd(amb_cnt, loc_cnt) : 0;
  __syncthreads();

  // compact copy-out: one coalesced 1KB zamb row per ambiguous token.
  // Source loads are strided but L2-hot (just staged by this block).
  int cnt = loc_cnt;
  int base = loc_base;
  const float* zcol = z + (size_t)b * ED * S + s0;
  for (int k = 0; k < cnt; ++k) {
    int lt = loc_tok[k];
    int gpos = base + k;
    if (gpos < TOKENS) {
      if (tid == 0) amb_list[gpos] = t0 + lt;
      if (gpos < zcap)
        zamb[(size_t)gpos * ED + tid] = zcol[(size_t)tid * S + lt];
    }
  }
}

// ---------------- exact-np rescan: 8 tokens/block, 4 codes/thread ----------------
// Thread tid owns codes [4*tid, 4*tid+4) for ALL 8 tokens of the tile.
// emb is read via embT[c][j] so the 4 codes' channel-c values are ONE contiguous
// float4 per lane, consecutive across lanes (fully coalesced: 16 lines/wave-load
// instead of 64 with row-major emb -> removes the TA serialization that pinned
// this kernel at 154us). z rows come from the compacted zamb buffer.
// Bitwise round-3/4 formula preserved: per-(token,code) ascending-c fmaf chain
// (one fmaf per channel, same order as the row-major float4 x,y,z,w walk),
// ||z||^2 chain folded in the same ascending-c loop, d = fl(fl(A+B) - 2M).
// Argmin: in-thread strict-< over ascending codes, then associative lex-(d,j)
// tree reduce == first-index-among-ties.
#define RT 8
__global__ void __launch_bounds__(256)
k_rescan(const float* __restrict__ z, const float* __restrict__ embT,
         const float* __restrict__ en, const int* __restrict__ amb_cnt,
         const int* __restrict__ amb_list, const float* __restrict__ zamb,
         int zcap, float* __restrict__ out_idx) {
#pragma clang fp contract(off)
  __shared__ float zs[RT][256];
  __shared__ float m1s[RT][256];
  __shared__ int   jms[RT][256];
  int n = *amb_cnt;
  if (n > TOKENS) n = TOKENS;
  int ntiles = (n + RT - 1) / RT;
  int tid = threadIdx.x;
  int j0 = tid * 4;

  for (int tile = blockIdx.x; tile < ntiles; tile += gridDim.x) {
    __syncthreads();                       // protect zs/m1s reuse across tiles
#pragma unroll
    for (int it = 0; it < RT; ++it) {
      int i = tile * RT + it;
      int li = i < n ? i : n - 1;
      if (li < zcap) {
        zs[it][tid] = zamb[(size_t)li * ED + tid];       // coalesced row
      } else {
        int t = amb_list[li];
        int b = t >> 15, s = t & 32767;
        zs[it][tid] = z[(size_t)b * ED * S + (size_t)tid * S + s];
      }
    }
    __syncthreads();

    float A[RT], a0[RT], a1[RT], a2[RT], a3[RT];
#pragma unroll
    for (int tk = 0; tk < RT; ++tk) {
      A[tk] = 0.f; a0[tk] = 0.f; a1[tk] = 0.f; a2[tk] = 0.f; a3[tk] = 0.f;
    }
    for (int c = 0; c < ED; c += 4) {
      // q{0..3} = codes [j0..j0+3] at channels c..c+3 (coalesced across lanes)
      float4 q0 = *(const float4*)(embT + (size_t)(c + 0) * NE + j0);
      float4 q1 = *(const float4*)(embT + (size_t)(c + 1) * NE + j0);
      float4 q2 = *(const float4*)(embT + (size_t)(c + 2) * NE + j0);
      float4 q3 = *(const float4*)(embT + (size_t)(c + 3) * NE + j0);
#pragma unroll
      for (int tk = 0; tk < RT; ++tk) {
        float4 zv = *(const float4*)(&zs[tk][c]);
        A[tk] = fmaf(zv.x, zv.x, A[tk]); A[tk] = fmaf(zv.y, zv.y, A[tk]);
        A[tk] = fmaf(zv.z, zv.z, A[tk]); A[tk] = fmaf(zv.w, zv.w, A[tk]);
        // code j0+0: channels c, c+1, c+2, c+3 (ascending, same as row-major walk)
        a0[tk] = fmaf(zv.x, q0.x, a0[tk]); a0[tk] = fmaf(zv.y, q1.x, a0[tk]);
        a0[tk] = fmaf(zv.z, q2.x, a0[tk]); a0[tk] = fmaf(zv.w, q3.x, a0[tk]);
        a1[tk] = fmaf(zv.x, q0.y, a1[tk]); a1[tk] = fmaf(zv.y, q1.y, a1[tk]);
        a1[tk] = fmaf(zv.z, q2.y, a1[tk]); a1[tk] = fmaf(zv.w, q3.y, a1[tk]);
        a2[tk] = fmaf(zv.x, q0.z, a2[tk]); a2[tk] = fmaf(zv.y, q1.z, a2[tk]);
        a2[tk] = fmaf(zv.z, q2.z, a2[tk]); a2[tk] = fmaf(zv.w, q3.z, a2[tk]);
        a3[tk] = fmaf(zv.x, q0.w, a3[tk]); a3[tk] = fmaf(zv.y, q1.w, a3[tk]);
        a3[tk] = fmaf(zv.z, q2.w, a3[tk]); a3[tk] = fmaf(zv.w, q3.w, a3[tk]);
      }
    }

    float e0n = en[j0 + 0], e1n = en[j0 + 1], e2n = en[j0 + 2], e3n = en[j0 + 3];
#pragma unroll
    for (int tk = 0; tk < RT; ++tk) {
      float d0 = (A[tk] + e0n) - 2.f * a0[tk];
      float d1 = (A[tk] + e1n) - 2.f * a1[tk];
      float d2 = (A[tk] + e2n) - 2.f * a2[tk];
      float d3 = (A[tk] + e3n) - 2.f * a3[tk];
      float bm = d0; int bi = j0;
      if (d1 < bm) { bm = d1; bi = j0 + 1; }
      if (d2 < bm) { bm = d2; bi = j0 + 2; }
      if (d3 < bm) { bm = d3; bi = j0 + 3; }
      m1s[tk][tid] = bm; jms[tk][tid] = bi;
    }
    __syncthreads();

    for (int off = 128; off > 0; off >>= 1) {
      if (tid < off) {
#pragma unroll
        for (int tk = 0; tk < RT; ++tk) {
          float dv = m1s[tk][tid + off]; int jv = jms[tk][tid + off];
          float dc = m1s[tk][tid];       int jc = jms[tk][tid];
          if (dv < dc || (dv == dc && jv < jc)) {
            m1s[tk][tid] = dv; jms[tk][tid] = jv;
          }
        }
      }
      __syncthreads();
    }

    if (tid < RT) {
      int i = tile * RT + tid;
      if (i < n) out_idx[amb_list[i]] = (float)jms[tid][0];
    }
  }
}

// ---------------- epilogue: z_q gather + loss + sampled ----------------
__global__ void __launch_bounds__(256)
k_epi(const float* __restrict__ z, const float* __restrict__ emb,
      const float* __restrict__ idxf, float* __restrict__ out_zq,
      float* __restrict__ out_samp, float* __restrict__ out_loss) {
  __shared__ float red[256];
  int tid = threadIdx.x;
  int lane = tid & 63;
  int w = tid >> 6;
  int t0 = blockIdx.x * 64;
  int b = t0 >> 15;
  int s0 = t0 & 32767;

  int jm = (int)idxf[t0 + lane];
  if (w == 0) out_samp[jm] = 1.0f;     // idx < 1024 -> always row 0

  const float* zb = z + ((size_t)b * ED * S) + s0;
  float* zqb = out_zq + ((size_t)b * ED * S) + s0;
  const float* erow = emb + (size_t)jm * ED;
  float lacc = 0.f;
  for (int cc = w; cc < ED; cc += 4) {
    float zq = erow[cc];
    float zv = zb[(size_t)cc * S + lane];
    float df = zq - zv;
    lacc = fmaf(df, df, lacc);
    zqb[(size_t)cc * S + lane] = zq;
  }
  red[tid] = lacc;
  __syncthreads();
  for (int off = 128; off > 0; off >>= 1) {
    if (tid < off) red[tid] += red[tid + off];
    __syncthreads();
  }
  if (tid == 0)
    atomicAdd(out_loss, red[0] * (1.2f / 16777216.0f));  // (1+BETA)*mean
}

// ---------------- codebook self-distance: LDS-tiled fp32 GEMM ----------------
__global__ void __launch_bounds__(256)
k_cd(const float* __restrict__ emb, const float* __restrict__ en,
     float* __restrict__ cd) {
  __shared__ float At[64 * 260];
  __shared__ float Bt[64 * 260];
  int bi = blockIdx.x >> 4, bj = blockIdx.x & 15;
  int tid = threadIdx.x;
  const float4* ev = (const float4*)emb;
  for (int idx = tid; idx < 64 * 64; idx += 256) {
    int row = idx >> 6, c4 = idx & 63;
    *(float4*)(&At[row * 260 + c4 * 4]) = ev[(size_t)(bi * 64 + row) * 64 + c4];
    *(float4*)(&Bt[row * 260 + c4 * 4]) = ev[(size_t)(bj * 64 + row) * 64 + c4];
  }
  __syncthreads();
  int ti = tid & 15, tj = tid >> 4;
  float acc[4][4] = {};
  for (int c = 0; c < ED; c += 4) {
    float4 a[4], bq[4];
#pragma unroll
    for (int p = 0; p < 4; ++p) a[p] = *(const float4*)(&At[(ti * 4 + p) * 260 + c]);
#pragma unroll
    for (int q = 0; q < 4; ++q) bq[q] = *(const float4*)(&Bt[(tj * 4 + q) * 260 + c]);
#pragma unroll
    for (int p = 0; p < 4; ++p)
#pragma unroll
      for (int q = 0; q < 4; ++q) {
        acc[p][q] = fmaf(a[p].x, bq[q].x, acc[p][q]);
        acc[p][q] = fmaf(a[p].y, bq[q].y, acc[p][q]);
        acc[p][q] = fmaf(a[p].z, bq[q].z, acc[p][q]);
        acc[p][q] = fmaf(a[p].w, bq[q].w, acc[p][q]);
      }
  }
#pragma unroll
  for (int p = 0; p < 4; ++p)
#pragma unroll
    for (int q = 0; q < 4; ++q) {
      int i = bi * 64 + ti * 4 + p;
      int j = bj * 64 + tj * 4 + q;
      cd[(size_t)i * NE + j] = (en[i] + en[j]) - 2.f * acc[p][q];
    }
}

// ---------------- per-column 2nd smallest -> mean ----------------
// 64 blocks x 16 cols; 16 row-chunks of 64 per column, LDS merge.
__global__ void __launch_bounds__(256)
k_colstats(const float* __restrict__ cd, float* __restrict__ out_md) {
  int tid = threadIdx.x;
  int j = blockIdx.x * 16 + (tid & 15);
  int chunk = tid >> 4;
  float m1 = 3.4e38f, m2 = 3.4e38f;
  int r0 = chunk * 64;
  for (int r = r0; r < r0 + 64; ++r) {
    float v = cd[(size_t)r * NE + j];
    if (v < m1) { m2 = m1; m1 = v; }
    else if (v < m2) { m2 = v; }
  }
  __shared__ float s1[256], s2[256];
  s1[tid] = m1; s2[tid] = m2;
  __syncthreads();
  if (chunk == 0) {
    for (int cc = 1; cc < 16; ++cc) {
      float n1 = s1[cc * 16 + tid], n2 = s2[cc * 16 + tid];
      float lo = fminf(m1, n1);
      float hi = fmaxf(m1, n1);
      m2 = fminf(hi, fminf(m2, n2));
      m1 = lo;
    }
    atomicAdd(out_md, m2 * (1.0f / 1024.0f));
  }
}

// ---------------- per-row variance (ddof=1) -> mean ----------------
__global__ void k_var(const float* __restrict__ cd, float* __restrict__ out_mv) {
  int i = blockIdx.x;
  int tid = threadIdx.x;
  const float* row = cd + (size_t)i * NE;
  __shared__ float red[256];
  float s = row[tid] + row[tid + 256] + row[tid + 512] + row[tid + 768];
  red[tid] = s;
  __syncthreads();
  for (int off = 128; off > 0; off >>= 1) {
    if (tid < off) red[tid] += red[tid + off];
    __syncthreads();
  }
  float mean = red[0] * (1.0f / 1024.0f);
  __syncthreads();
  float d0 = row[tid] - mean, d1 = row[tid + 256] - mean,
        d2 = row[tid + 512] - mean, d3 = row[tid + 768] - mean;
  red[tid] = d0 * d0 + d1 * d1 + d2 * d2 + d3 * d3;
  __syncthreads();
  for (int off = 128; off > 0; off >>= 1) {
    if (tid < off) red[tid] += red[tid + off];
    __syncthreads();
  }
  if (tid == 0)
    atomicAdd(out_mv, red[0] * (1.0f / 1023.0f) * (1.0f / 1024.0f));
}

extern "C" void kernel_launch(void* const* d_in, const int* in_sizes, int n_in,
                              void* d_out, int out_size, void* d_ws, size_t ws_size,
                              hipStream_t stream) {
  const float* z   = (const float*)d_in[0];
  const float* emb = (const float*)d_in[1];
  float* out = (float*)d_out;

  float* cd = (float*)d_ws;                       // 4 MiB
  float* en = cd + (size_t)NE * NE;               // 4 KiB
  _Float16* embf = (_Float16*)(en + NE);          // 512 KiB fragment-ordered fp16
  int* amb_cnt = (int*)(embf + (size_t)NE * ED);
  int* amb_list = amb_cnt + 16;                   // TOKENS ints (256 KiB)
  float* embT = (float*)(amb_list + TOKENS);      // 1 MiB transposed codebook
  float* zamb = embT + (size_t)ED * NE;           // compacted z rows (1KB each)

  // zcap from actual workspace size: graceful fallback if ws is small.
  size_t base_bytes = (size_t)((char*)zamb - (char*)d_ws);
  int zcap = 0;
  if (ws_size > base_bytes) {
    size_t rows = (ws_size - base_bytes) / ((size_t)ED * sizeof(float));
    zcap = rows > (size_t)ZCAP_MAX ? ZCAP_MAX : (int)rows;
  }

  hipMemsetAsync(out + OFF_LOSS, 0,
                 (size_t)(out_size - OFF_LOSS) * sizeof(float), stream);
  hipMemsetAsync(amb_cnt, 0, sizeof(int), stream);

  k_enorm<<<NE / 256, 256, 0, stream>>>(emb, en);
  k_cvt<<<64, 512, 0, stream>>>(emb, embf);
  k_tr<<<256, 256, 0, stream>>>(emb, embT);
  k_filter<<<TOKENS / 128, 256, 0, stream>>>(z, embf, en, out + OFF_IDX,
                                             amb_cnt, amb_list, zamb, zcap);
  k_rescan<<<2048, 256, 0, stream>>>(z, embT, en, amb_cnt, amb_list,
                                     zamb, zcap, out + OFF_IDX);
  k_epi<<<TOKENS / 64, 256, 0, stream>>>(z, emb, out + OFF_IDX,
                                         out, out + OFF_SAMP, out + OFF_LOSS);
  k_cd<<<256, 256, 0, stream>>>(emb, en, cd);
  k_colstats<<<64, 256, 0, stream>>>(cd, out + OFF_MD);
  k_var<<<NE, 256, 0, stream>>>(cd, out + OFF_MV);
}

// Round 6
// 333.324 us; speedup vs baseline: 1.5566x; 1.1862x over previous
//
#include <hip/hip_runtime.h>
#include <stdint.h>

#define NE   1024
#define ED   256
#define NB   2
#define S    32768            // 32*32*32
#define TOKENS (NB*S)         // 65536

#define OFF_LOSS 16777216
#define OFF_IDX  16777217
#define OFF_SAMP 16842753
#define OFF_MD   16844801
#define OFF_MV   16844802

#define TAU 2.5e-4f           // fp16-filter ambiguity margin (~6 sigma of 3e-5 err)
#define ZCAP_MAX 16384        // max compacted z rows (16.8 MiB)

typedef _Float16 half8 __attribute__((ext_vector_type(8)));
typedef float floatx4 __attribute__((ext_vector_type(4)));

// ---------------- codebook norms: bitwise numpy pairwise sum ----------------
__global__ void k_enorm(const float* __restrict__ emb, float* __restrict__ en) {
#pragma clang fp contract(off)
  int j = blockIdx.x * 256 + threadIdx.x;
  const float* e = emb + (size_t)j * ED;
  float halves[2];
  for (int h = 0; h < 2; ++h) {
    const float* a = e + h * 128;
    float r[8];
    for (int k = 0; k < 8; ++k) r[k] = a[k] * a[k];
    for (int i = 8; i < 128; i += 8)
      for (int k = 0; k < 8; ++k) r[k] += a[i + k] * a[i + k];
    halves[h] = ((r[0] + r[1]) + (r[2] + r[3])) + ((r[4] + r[5]) + (r[6] + r[7]));
  }
  en[j] = halves[0] + halves[1];
}

// ---------------- emb -> fragment-ordered fp16 ----------------
__global__ void k_cvt(const float* __restrict__ emb, _Float16* __restrict__ embf) {
  int g = blockIdx.x * 512 + threadIdx.x;   // 64 blocks x 512 = 32768
  int lane = g & 63;
  int ks = (g >> 6) & 7;
  int nt = g >> 9;
  int n = nt * 16 + (lane & 15);
  int k0 = ks * 32 + (lane >> 4) * 8;
  const float* src = emb + (size_t)n * ED + k0;
  half8 v;
#pragma unroll
  for (int j = 0; j < 8; ++j) v[j] = (_Float16)src[j];
  *(half8*)(embf + ((size_t)((nt * 8 + ks) * 64 + lane)) * 8) = v;
}

// ---------------- emb -> transposed fp32 embT[c][j] (for coalesced rescan) ----
__global__ void __launch_bounds__(256)
k_tr(const float* __restrict__ emb, float* __restrict__ embT) {
  __shared__ float t[32][33];
  int bj = blockIdx.x >> 3;            // 0..31: code tile
  int bc = blockIdx.x & 7;             // 0..7 : channel tile
  int tx = threadIdx.x & 31, ty = threadIdx.x >> 5;
  int j0 = bj * 32, c0 = bc * 32;
#pragma unroll
  for (int k = 0; k < 4; ++k)
    t[ty + 8 * k][tx] = emb[(size_t)(j0 + ty + 8 * k) * ED + c0 + tx];
  __syncthreads();
#pragma unroll
  for (int k = 0; k < 4; ++k)
    embT[(size_t)(c0 + ty + 8 * k) * NE + j0 + tx] = t[tx][ty + 8 * k];
}

// ---------------- MFMA filter: approx argmin + top-2 ambiguity ----------------
// 128 tokens/block, 256 thr = 4 waves; wave w owns tokens [w*32, w*32+32).
// The embf B-stream is staged through LDS, shared by all 4 waves. Previously
// each of the 2048 waves streamed the full 512 KB embf through L1/L2
// independently (4 MB/CU L1 traffic, 128 MB/XCD L2 traffic) -- the 136us
// limiter. The 67.5 KB zA region is DEAD after the A-frags are
// register-resident, so it is reused as a double-buffered B stage:
// 2 buffers x 4 tiles x 8 KB. Per chunk each wave reg-stages one tile
// (T14 split: loads issued before compute, ds_write after), 1 barrier/chunk.
__global__ void __launch_bounds__(256)
k_filter(const float* __restrict__ z, const _Float16* __restrict__ embf,
         const float* __restrict__ en, float* __restrict__ out_idx,
         int* __restrict__ amb_cnt, int* __restrict__ amb_list,
         float* __restrict__ zamb, int zcap) {
  __shared__ __align__(16) char smem[128 * 264 * 2];  // zA region, reused as B dbuf
  __shared__ float en_s[NE];
  __shared__ int loc_cnt, loc_base;
  __shared__ int loc_tok[128];
  _Float16* zA = (_Float16*)smem;      // [tok][264] during phase 1

  int tid = threadIdx.x;
  int lane = tid & 63;
  int w = tid >> 6;
  int mrow = lane & 15;
  int quad = lane >> 4;
  int t0 = blockIdx.x * 128;
  int b = t0 >> 15;                    // 32768 % 128 == 0: no straddle
  int s0 = t0 & 32767;

  if (tid == 0) loc_cnt = 0;
  for (int i = tid; i < NE; i += 256) en_s[i] = en[i];

  {  // stage z tile -> fp16 LDS (coalesced along s, rne convert)
    int tok = tid & 127;
    int ch = tid >> 7;
    const float* zb = z + (size_t)b * ED * S + s0 + tok;
    for (int it = 0; it < 16; ++it) {
      int c0 = ch * 8 + it * 16;
      half8 v;
#pragma unroll
      for (int j = 0; j < 8; ++j) v[j] = (_Float16)zb[(size_t)(c0 + j) * S];
      *(half8*)(&zA[tok * 264 + c0]) = v;
    }
  }
  __syncthreads();

  // A-frags register-resident: af[stripe][kstep]
  half8 af[2][8];
#pragma unroll
  for (int s = 0; s < 2; ++s)
#pragma unroll
    for (int ks = 0; ks < 8; ++ks)
      af[s][ks] = *(const half8*)(&zA[(w * 32 + s * 16 + mrow) * 264 + ks * 32 + quad * 8]);

  __syncthreads();                     // zA dead -> region becomes B dbuf

  float m1[2][4], m2[2][4];
  int j1[2][4];
#pragma unroll
  for (int s = 0; s < 2; ++s)
#pragma unroll
    for (int r = 0; r < 4; ++r) { m1[s][r] = 3.4e38f; m2[s][r] = 3.4e38f; j1[s][r] = 0; }

  // prologue: stage chunk 0 (tiles 0..3; wave w stages tile w = 8 KB)
  {
    const half8* g = (const half8*)embf + (size_t)w * 512 + lane;
    half8 st[8];
#pragma unroll
    for (int i = 0; i < 8; ++i) st[i] = g[i * 64];
    _Float16* l = (_Float16*)(smem + w * 8192);
#pragma unroll
    for (int i = 0; i < 8; ++i) *(half8*)(l + i * 512 + lane * 8) = st[i];
  }
  __syncthreads();

  int buf = 0;
  for (int chunk = 0; chunk < 16; ++chunk) {
    // T14: issue next chunk's global loads BEFORE compute (hide L2 latency)
    half8 st[8];
    bool pf = chunk < 15;
    if (pf) {
      const half8* g = (const half8*)embf + ((size_t)(chunk + 1) * 4 + w) * 512 + lane;
#pragma unroll
      for (int i = 0; i < 8; ++i) st[i] = g[i * 64];
    }

    // compute 4 tiles from buf (B values bit-identical to the L2-direct path)
#pragma unroll
    for (int ntl = 0; ntl < 4; ++ntl) {
      int nt = chunk * 4 + ntl;
      const half8* pb = (const half8*)(smem + buf * 32768 + ntl * 8192) + lane;
      floatx4 acc0 = {0.f, 0.f, 0.f, 0.f}, acc1 = {0.f, 0.f, 0.f, 0.f};
#pragma unroll
      for (int ks = 0; ks < 8; ++ks) {
        half8 bf = pb[ks * 64];
        acc0 = __builtin_amdgcn_mfma_f32_16x16x32_f16(af[0][ks], bf, acc0, 0, 0, 0);
        acc1 = __builtin_amdgcn_mfma_f32_16x16x32_f16(af[1][ks], bf, acc1, 0, 0, 0);
      }
      int j = nt * 16 + mrow;
      float Bj = en_s[j];              // ||z||^2 constant per token -> dropped
#pragma unroll
      for (int r = 0; r < 4; ++r) {    // branchless == original if/elif semantics
        float d0 = Bj - 2.f * acc0[r];
        float d1 = Bj - 2.f * acc1[r];
        bool l0 = d0 < m1[0][r];
        m2[0][r] = l0 ? m1[0][r] : fminf(m2[0][r], d0);
        j1[0][r] = l0 ? j : j1[0][r];
        m1[0][r] = l0 ? d0 : m1[0][r];
        bool l1 = d1 < m1[1][r];
        m2[1][r] = l1 ? m1[1][r] : fminf(m2[1][r], d1);
        j1[1][r] = l1 ? j : j1[1][r];
        m1[1][r] = l1 ? d1 : m1[1][r];
      }
    }

    // land the prefetched tile into the other buffer
    if (pf) {
      _Float16* l = (_Float16*)(smem + (buf ^ 1) * 32768 + w * 8192);
#pragma unroll
      for (int i = 0; i < 8; ++i) *(half8*)(l + i * 512 + lane * 8) = st[i];
    }
    __syncthreads();
    buf ^= 1;
  }

  // merge across the 16 lanes of each quad (same tokens, different codes)
#pragma unroll
  for (int d = 1; d < 16; d <<= 1) {
#pragma unroll
    for (int s = 0; s < 2; ++s)
#pragma unroll
      for (int r = 0; r < 4; ++r) {
        float om1 = __shfl_xor(m1[s][r], d, 64);
        float om2 = __shfl_xor(m2[s][r], d, 64);
        int oj = __shfl_xor(j1[s][r], d, 64);
        float hi;
        if (om1 < m1[s][r] || (om1 == m1[s][r] && oj < j1[s][r])) {
          hi = m1[s][r]; m1[s][r] = om1; j1[s][r] = oj;
        } else hi = om1;                 // equal-m1 merges force m2==m1 -> flagged
        m2[s][r] = fminf(m2[s][r], fminf(om2, hi));
      }
  }

  if (mrow == 0) {
#pragma unroll
    for (int s = 0; s < 2; ++s)
#pragma unroll
      for (int r = 0; r < 4; ++r) {
        int tok = w * 32 + s * 16 + quad * 4 + r;
        out_idx[t0 + tok] = (float)j1[s][r];
        if (m2[s][r] - m1[s][r] < TAU) {
          int p = atomicAdd(&loc_cnt, 1);
          loc_tok[p] = tok;
        }
      }
  }
  __syncthreads();
  if (tid == 0) loc_base = (loc_cnt > 0) ? atomicAdd(amb_cnt, loc_cnt) : 0;
  __syncthreads();

  // compact copy-out: one coalesced 1KB zamb row per ambiguous token.
  int cnt = loc_cnt;
  int base = loc_base;
  const float* zcol = z + (size_t)b * ED * S + s0;
  for (int k = 0; k < cnt; ++k) {
    int lt = loc_tok[k];
    int gpos = base + k;
    if (gpos < TOKENS) {
      if (tid == 0) amb_list[gpos] = t0 + lt;
      if (gpos < zcap)
        zamb[(size_t)gpos * ED + tid] = zcol[(size_t)tid * S + lt];
    }
  }
}

// ---------------- exact-np rescan: 8 tokens/block, 4 codes/thread ----------------
// Thread tid owns codes [4*tid, 4*tid+4) for ALL 8 tokens of the tile.
// emb read via embT[c][j]: fully coalesced. z rows from compacted zamb.
// Bitwise round-3/4 formula preserved (ascending-c fmaf chains, lex-(d,j)).
#define RT 8
__global__ void __launch_bounds__(256)
k_rescan(const float* __restrict__ z, const float* __restrict__ embT,
         const float* __restrict__ en, const int* __restrict__ amb_cnt,
         const int* __restrict__ amb_list, const float* __restrict__ zamb,
         int zcap, float* __restrict__ out_idx) {
#pragma clang fp contract(off)
  __shared__ float zs[RT][256];
  __shared__ float m1s[RT][256];
  __shared__ int   jms[RT][256];
  int n = *amb_cnt;
  if (n > TOKENS) n = TOKENS;
  int ntiles = (n + RT - 1) / RT;
  int tid = threadIdx.x;
  int j0 = tid * 4;

  for (int tile = blockIdx.x; tile < ntiles; tile += gridDim.x) {
    __syncthreads();                       // protect zs/m1s reuse across tiles
#pragma unroll
    for (int it = 0; it < RT; ++it) {
      int i = tile * RT + it;
      int li = i < n ? i : n - 1;
      if (li < zcap) {
        zs[it][tid] = zamb[(size_t)li * ED + tid];       // coalesced row
      } else {
        int t = amb_list[li];
        int b = t >> 15, s = t & 32767;
        zs[it][tid] = z[(size_t)b * ED * S + (size_t)tid * S + s];
      }
    }
    __syncthreads();

    float A[RT], a0[RT], a1[RT], a2[RT], a3[RT];
#pragma unroll
    for (int tk = 0; tk < RT; ++tk) {
      A[tk] = 0.f; a0[tk] = 0.f; a1[tk] = 0.f; a2[tk] = 0.f; a3[tk] = 0.f;
    }
    for (int c = 0; c < ED; c += 4) {
      float4 q0 = *(const float4*)(embT + (size_t)(c + 0) * NE + j0);
      float4 q1 = *(const float4*)(embT + (size_t)(c + 1) * NE + j0);
      float4 q2 = *(const float4*)(embT + (size_t)(c + 2) * NE + j0);
      float4 q3 = *(const float4*)(embT + (size_t)(c + 3) * NE + j0);
#pragma unroll
      for (int tk = 0; tk < RT; ++tk) {
        float4 zv = *(const float4*)(&zs[tk][c]);
        A[tk] = fmaf(zv.x, zv.x, A[tk]); A[tk] = fmaf(zv.y, zv.y, A[tk]);
        A[tk] = fmaf(zv.z, zv.z, A[tk]); A[tk] = fmaf(zv.w, zv.w, A[tk]);
        a0[tk] = fmaf(zv.x, q0.x, a0[tk]); a0[tk] = fmaf(zv.y, q1.x, a0[tk]);
        a0[tk] = fmaf(zv.z, q2.x, a0[tk]); a0[tk] = fmaf(zv.w, q3.x, a0[tk]);
        a1[tk] = fmaf(zv.x, q0.y, a1[tk]); a1[tk] = fmaf(zv.y, q1.y, a1[tk]);
        a1[tk] = fmaf(zv.z, q2.y, a1[tk]); a1[tk] = fmaf(zv.w, q3.y, a1[tk]);
        a2[tk] = fmaf(zv.x, q0.z, a2[tk]); a2[tk] = fmaf(zv.y, q1.z, a2[tk]);
        a2[tk] = fmaf(zv.z, q2.z, a2[tk]); a2[tk] = fmaf(zv.w, q3.z, a2[tk]);
        a3[tk] = fmaf(zv.x, q0.w, a3[tk]); a3[tk] = fmaf(zv.y, q1.w, a3[tk]);
        a3[tk] = fmaf(zv.z, q2.w, a3[tk]); a3[tk] = fmaf(zv.w, q3.w, a3[tk]);
      }
    }

    float e0n = en[j0 + 0], e1n = en[j0 + 1], e2n = en[j0 + 2], e3n = en[j0 + 3];
#pragma unroll
    for (int tk = 0; tk < RT; ++tk) {
      float d0 = (A[tk] + e0n) - 2.f * a0[tk];
      float d1 = (A[tk] + e1n) - 2.f * a1[tk];
      float d2 = (A[tk] + e2n) - 2.f * a2[tk];
      float d3 = (A[tk] + e3n) - 2.f * a3[tk];
      float bm = d0; int bi = j0;
      if (d1 < bm) { bm = d1; bi = j0 + 1; }
      if (d2 < bm) { bm = d2; bi = j0 + 2; }
      if (d3 < bm) { bm = d3; bi = j0 + 3; }
      m1s[tk][tid] = bm; jms[tk][tid] = bi;
    }
    __syncthreads();

    for (int off = 128; off > 0; off >>= 1) {
      if (tid < off) {
#pragma unroll
        for (int tk = 0; tk < RT; ++tk) {
          float dv = m1s[tk][tid + off]; int jv = jms[tk][tid + off];
          float dc = m1s[tk][tid];       int jc = jms[tk][tid];
          if (dv < dc || (dv == dc && jv < jc)) {
            m1s[tk][tid] = dv; jms[tk][tid] = jv;
          }
        }
      }
      __syncthreads();
    }

    if (tid < RT) {
      int i = tile * RT + tid;
      if (i < n) out_idx[amb_list[i]] = (float)jms[tid][0];
    }
  }
}

// ---------------- epilogue: z_q gather + loss + sampled ----------------
__global__ void __launch_bounds__(256)
k_epi(const float* __restrict__ z, const float* __restrict__ emb,
      const float* __restrict__ idxf, float* __restrict__ out_zq,
      float* __restrict__ out_samp, float* __restrict__ out_loss) {
  __shared__ float red[256];
  int tid = threadIdx.x;
  int lane = tid & 63;
  int w = tid >> 6;
  int t0 = blockIdx.x * 64;
  int b = t0 >> 15;
  int s0 = t0 & 32767;

  int jm = (int)idxf[t0 + lane];
  if (w == 0) out_samp[jm] = 1.0f;     // idx < 1024 -> always row 0

  const float* zb = z + ((size_t)b * ED * S) + s0;
  float* zqb = out_zq + ((size_t)b * ED * S) + s0;
  const float* erow = emb + (size_t)jm * ED;
  float lacc = 0.f;
  for (int cc = w; cc < ED; cc += 4) {
    float zq = erow[cc];
    float zv = zb[(size_t)cc * S + lane];
    float df = zq - zv;
    lacc = fmaf(df, df, lacc);
    zqb[(size_t)cc * S + lane] = zq;
  }
  red[tid] = lacc;
  __syncthreads();
  for (int off = 128; off > 0; off >>= 1) {
    if (tid < off) red[tid] += red[tid + off];
    __syncthreads();
  }
  if (tid == 0)
    atomicAdd(out_loss, red[0] * (1.2f / 16777216.0f));  // (1+BETA)*mean
}

// ---------------- codebook self-distance: LDS-tiled fp32 GEMM ----------------
__global__ void __launch_bounds__(256)
k_cd(const float* __restrict__ emb, const float* __restrict__ en,
     float* __restrict__ cd) {
  __shared__ float At[64 * 260];
  __shared__ float Bt[64 * 260];
  int bi = blockIdx.x >> 4, bj = blockIdx.x & 15;
  int tid = threadIdx.x;
  const float4* ev = (const float4*)emb;
  for (int idx = tid; idx < 64 * 64; idx += 256) {
    int row = idx >> 6, c4 = idx & 63;
    *(float4*)(&At[row * 260 + c4 * 4]) = ev[(size_t)(bi * 64 + row) * 64 + c4];
    *(float4*)(&Bt[row * 260 + c4 * 4]) = ev[(size_t)(bj * 64 + row) * 64 + c4];
  }
  __syncthreads();
  int ti = tid & 15, tj = tid >> 4;
  float acc[4][4] = {};
  for (int c = 0; c < ED; c += 4) {
    float4 a[4], bq[4];
#pragma unroll
    for (int p = 0; p < 4; ++p) a[p] = *(const float4*)(&At[(ti * 4 + p) * 260 + c]);
#pragma unroll
    for (int q = 0; q < 4; ++q) bq[q] = *(const float4*)(&Bt[(tj * 4 + q) * 260 + c]);
#pragma unroll
    for (int p = 0; p < 4; ++p)
#pragma unroll
      for (int q = 0; q < 4; ++q) {
        acc[p][q] = fmaf(a[p].x, bq[q].x, acc[p][q]);
        acc[p][q] = fmaf(a[p].y, bq[q].y, acc[p][q]);
        acc[p][q] = fmaf(a[p].z, bq[q].z, acc[p][q]);
        acc[p][q] = fmaf(a[p].w, bq[q].w, acc[p][q]);
      }
  }
#pragma unroll
  for (int p = 0; p < 4; ++p)
#pragma unroll
    for (int q = 0; q < 4; ++q) {
      int i = bi * 64 + ti * 4 + p;
      int j = bj * 64 + tj * 4 + q;
      cd[(size_t)i * NE + j] = (en[i] + en[j]) - 2.f * acc[p][q];
    }
}

// ---------------- per-column 2nd smallest -> mean ----------------
__global__ void __launch_bounds__(256)
k_colstats(const float* __restrict__ cd, float* __restrict__ out_md) {
  int tid = threadIdx.x;
  int j = blockIdx.x * 16 + (tid & 15);
  int chunk = tid >> 4;
  float m1 = 3.4e38f, m2 = 3.4e38f;
  int r0 = chunk * 64;
  for (int r = r0; r < r0 + 64; ++r) {
    float v = cd[(size_t)r * NE + j];
    if (v < m1) { m2 = m1; m1 = v; }
    else if (v < m2) { m2 = v; }
  }
  __shared__ float s1[256], s2[256];
  s1[tid] = m1; s2[tid] = m2;
  __syncthreads();
  if (chunk == 0) {
    for (int cc = 1; cc < 16; ++cc) {
      float n1 = s1[cc * 16 + tid], n2 = s2[cc * 16 + tid];
      float lo = fminf(m1, n1);
      float hi = fmaxf(m1, n1);
      m2 = fminf(hi, fminf(m2, n2));
      m1 = lo;
    }
    atomicAdd(out_md, m2 * (1.0f / 1024.0f));
  }
}

// ---------------- per-row variance (ddof=1) -> mean ----------------
__global__ void k_var(const float* __restrict__ cd, float* __restrict__ out_mv) {
  int i = blockIdx.x;
  int tid = threadIdx.x;
  const float* row = cd + (size_t)i * NE;
  __shared__ float red[256];
  float s = row[tid] + row[tid + 256] + row[tid + 512] + row[tid + 768];
  red[tid] = s;
  __syncthreads();
  for (int off = 128; off > 0; off >>= 1) {
    if (tid < off) red[tid] += red[tid + off];
    __syncthreads();
  }
  float mean = red[0] * (1.0f / 1024.0f);
  __syncthreads();
  float d0 = row[tid] - mean, d1 = row[tid + 256] - mean,
        d2 = row[tid + 512] - mean, d3 = row[tid + 768] - mean;
  red[tid] = d0 * d0 + d1 * d1 + d2 * d2 + d3 * d3;
  __syncthreads();
  for (int off = 128; off > 0; off >>= 1) {
    if (tid < off) red[tid] += red[tid + off];
    __syncthreads();
  }
  if (tid == 0)
    atomicAdd(out_mv, red[0] * (1.0f / 1023.0f) * (1.0f / 1024.0f));
}

extern "C" void kernel_launch(void* const* d_in, const int* in_sizes, int n_in,
                              void* d_out, int out_size, void* d_ws, size_t ws_size,
                              hipStream_t stream) {
  const float* z   = (const float*)d_in[0];
  const float* emb = (const float*)d_in[1];
  float* out = (float*)d_out;

  float* cd = (float*)d_ws;                       // 4 MiB
  float* en = cd + (size_t)NE * NE;               // 4 KiB
  _Float16* embf = (_Float16*)(en + NE);          // 512 KiB fragment-ordered fp16
  int* amb_cnt = (int*)(embf + (size_t)NE * ED);
  int* amb_list = amb_cnt + 16;                   // TOKENS ints (256 KiB)
  float* embT = (float*)(amb_list + TOKENS);      // 1 MiB transposed codebook
  float* zamb = embT + (size_t)ED * NE;           // compacted z rows (1KB each)

  size_t base_bytes = (size_t)((char*)zamb - (char*)d_ws);
  int zcap = 0;
  if (ws_size > base_bytes) {
    size_t rows = (ws_size - base_bytes) / ((size_t)ED * sizeof(float));
    zcap = rows > (size_t)ZCAP_MAX ? ZCAP_MAX : (int)rows;
  }

  hipMemsetAsync(out + OFF_LOSS, 0,
                 (size_t)(out_size - OFF_LOSS) * sizeof(float), stream);
  hipMemsetAsync(amb_cnt, 0, sizeof(int), stream);

  k_enorm<<<NE / 256, 256, 0, stream>>>(emb, en);
  k_cvt<<<64, 512, 0, stream>>>(emb, embf);
  k_tr<<<256, 256, 0, stream>>>(emb, embT);
  k_filter<<<TOKENS / 128, 256, 0, stream>>>(z, embf, en, out + OFF_IDX,
                                             amb_cnt, amb_list, zamb, zcap);
  k_rescan<<<2048, 256, 0, stream>>>(z, embT, en, amb_cnt, amb_list,
                                     zamb, zcap, out + OFF_IDX);
  k_epi<<<TOKENS / 64, 256, 0, stream>>>(z, emb, out + OFF_IDX,
                                         out, out + OFF_SAMP, out + OFF_LOSS);
  k_cd<<<256, 256, 0, stream>>>(emb, en, cd);
  k_colstats<<<64, 256, 0, stream>>>(cd, out + OFF_MD);
  k_var<<<NE, 256, 0, stream>>>(cd, out + OFF_MV);
}

// Round 7
// 327.991 us; speedup vs baseline: 1.5819x; 1.0163x over previous
//
#include <hip/hip_runtime.h>
#include <stdint.h>

#define NE   1024
#define ED   256
#define NB   2
#define S    32768            // 32*32*32
#define TOKENS (NB*S)         // 65536

#define OFF_LOSS 16777216
#define OFF_IDX  16777217
#define OFF_SAMP 16842753
#define OFF_MD   16844801
#define OFF_MV   16844802

#define TAU 2.5e-4f           // fp16-filter ambiguity margin (~6 sigma of 3e-5 err)
#define ZCAP_MAX 16384        // max compacted z rows (16.8 MiB)

typedef _Float16 half8 __attribute__((ext_vector_type(8)));
typedef float floatx4 __attribute__((ext_vector_type(4)));

// ---------------- codebook norms: bitwise numpy pairwise sum ----------------
__global__ void k_enorm(const float* __restrict__ emb, float* __restrict__ en) {
#pragma clang fp contract(off)
  int j = blockIdx.x * 256 + threadIdx.x;
  const float* e = emb + (size_t)j * ED;
  float halves[2];
  for (int h = 0; h < 2; ++h) {
    const float* a = e + h * 128;
    float r[8];
    for (int k = 0; k < 8; ++k) r[k] = a[k] * a[k];
    for (int i = 8; i < 128; i += 8)
      for (int k = 0; k < 8; ++k) r[k] += a[i + k] * a[i + k];
    halves[h] = ((r[0] + r[1]) + (r[2] + r[3])) + ((r[4] + r[5]) + (r[6] + r[7]));
  }
  en[j] = halves[0] + halves[1];
}

// ---------------- emb -> fragment-ordered fp16 ----------------
__global__ void k_cvt(const float* __restrict__ emb, _Float16* __restrict__ embf) {
  int g = blockIdx.x * 512 + threadIdx.x;   // 64 blocks x 512 = 32768
  int lane = g & 63;
  int ks = (g >> 6) & 7;
  int nt = g >> 9;
  int n = nt * 16 + (lane & 15);
  int k0 = ks * 32 + (lane >> 4) * 8;
  const float* src = emb + (size_t)n * ED + k0;
  half8 v;
#pragma unroll
  for (int j = 0; j < 8; ++j) v[j] = (_Float16)src[j];
  *(half8*)(embf + ((size_t)((nt * 8 + ks) * 64 + lane)) * 8) = v;
}

// ---------------- emb -> transposed fp32 embT[c][j] (for coalesced rescan) ----
__global__ void __launch_bounds__(256)
k_tr(const float* __restrict__ emb, float* __restrict__ embT) {
  __shared__ float t[32][33];
  int bj = blockIdx.x >> 3;            // 0..31: code tile
  int bc = blockIdx.x & 7;             // 0..7 : channel tile
  int tx = threadIdx.x & 31, ty = threadIdx.x >> 5;
  int j0 = bj * 32, c0 = bc * 32;
#pragma unroll
  for (int k = 0; k < 4; ++k)
    t[ty + 8 * k][tx] = emb[(size_t)(j0 + ty + 8 * k) * ED + c0 + tx];
  __syncthreads();
#pragma unroll
  for (int k = 0; k < 4; ++k)
    embT[(size_t)(c0 + ty + 8 * k) * NE + j0 + tx] = t[tx][ty + 8 * k];
}

// ---------------- MFMA filter: approx argmin + top-2 ambiguity ----------------
// 128 tokens/block, 256 thr = 4 waves. B-stream LDS-shared (round 6).
// NEW (this round): z staging vectorized -- float4 along s (4 tokens/load),
// 32 loads/thread in 4 ILP-8 rounds instead of 128 scalar loads in 16 rounds.
// Same RNE converts, same zA layout -> bit-identical A fragments.
__global__ void __launch_bounds__(256)
k_filter(const float* __restrict__ z, const _Float16* __restrict__ embf,
         const float* __restrict__ en, float* __restrict__ out_idx,
         int* __restrict__ amb_cnt, int* __restrict__ amb_list,
         float* __restrict__ zamb, int zcap) {
  __shared__ __align__(16) char smem[128 * 264 * 2];  // zA region, reused as B dbuf
  __shared__ float en_s[NE];
  __shared__ int loc_cnt, loc_base;
  __shared__ int loc_tok[128];
  _Float16* zA = (_Float16*)smem;      // [tok][264] during phase 1

  int tid = threadIdx.x;
  int lane = tid & 63;
  int w = tid >> 6;
  int mrow = lane & 15;
  int quad = lane >> 4;
  int t0 = blockIdx.x * 128;
  int b = t0 >> 15;                    // 32768 % 128 == 0: no straddle
  int s0 = t0 & 32767;

  if (tid == 0) loc_cnt = 0;
  for (int i = tid; i < NE; i += 256) en_s[i] = en[i];

  {  // stage z tile -> fp16 LDS: float4 along s (4 tokens x 1 channel per load)
    int tok4 = (tid & 31) * 4;         // token group base
    int cg = tid >> 5;                 // 0..7: channel group of 32
    const float* zb = z + (size_t)b * ED * S + s0 + tok4;
    for (int cc = 0; cc < 32; cc += 8) {
      float4 v[8];
#pragma unroll
      for (int u = 0; u < 8; ++u)
        v[u] = *(const float4*)(zb + (size_t)(cg * 32 + cc + u) * S);
#pragma unroll
      for (int u = 0; u < 8; u += 2) {
        int c = cg * 32 + cc + u;
#pragma unroll
        for (int k = 0; k < 4; ++k) {
          union { _Float16 h[2]; uint32_t u32; } p;
          p.h[0] = (_Float16)((&v[u].x)[k]);
          p.h[1] = (_Float16)((&v[u + 1].x)[k]);
          *(uint32_t*)(&zA[(tok4 + k) * 264 + c]) = p.u32;
        }
      }
    }
  }
  __syncthreads();

  // A-frags register-resident: af[stripe][kstep]
  half8 af[2][8];
#pragma unroll
  for (int s = 0; s < 2; ++s)
#pragma unroll
    for (int ks = 0; ks < 8; ++ks)
      af[s][ks] = *(const half8*)(&zA[(w * 32 + s * 16 + mrow) * 264 + ks * 32 + quad * 8]);

  __syncthreads();                     // zA dead -> region becomes B dbuf

  float m1[2][4], m2[2][4];
  int j1[2][4];
#pragma unroll
  for (int s = 0; s < 2; ++s)
#pragma unroll
    for (int r = 0; r < 4; ++r) { m1[s][r] = 3.4e38f; m2[s][r] = 3.4e38f; j1[s][r] = 0; }

  // prologue: stage chunk 0 (tiles 0..3; wave w stages tile w = 8 KB)
  {
    const half8* g = (const half8*)embf + (size_t)w * 512 + lane;
    half8 st[8];
#pragma unroll
    for (int i = 0; i < 8; ++i) st[i] = g[i * 64];
    _Float16* l = (_Float16*)(smem + w * 8192);
#pragma unroll
    for (int i = 0; i < 8; ++i) *(half8*)(l + i * 512 + lane * 8) = st[i];
  }
  __syncthreads();

  int buf = 0;
  for (int chunk = 0; chunk < 16; ++chunk) {
    // T14: issue next chunk's global loads BEFORE compute (hide L2 latency)
    half8 st[8];
    bool pf = chunk < 15;
    if (pf) {
      const half8* g = (const half8*)embf + ((size_t)(chunk + 1) * 4 + w) * 512 + lane;
#pragma unroll
      for (int i = 0; i < 8; ++i) st[i] = g[i * 64];
    }

    // compute 4 tiles from buf (B values bit-identical to the L2-direct path)
#pragma unroll
    for (int ntl = 0; ntl < 4; ++ntl) {
      int nt = chunk * 4 + ntl;
      const half8* pb = (const half8*)(smem + buf * 32768 + ntl * 8192) + lane;
      floatx4 acc0 = {0.f, 0.f, 0.f, 0.f}, acc1 = {0.f, 0.f, 0.f, 0.f};
#pragma unroll
      for (int ks = 0; ks < 8; ++ks) {
        half8 bf = pb[ks * 64];
        acc0 = __builtin_amdgcn_mfma_f32_16x16x32_f16(af[0][ks], bf, acc0, 0, 0, 0);
        acc1 = __builtin_amdgcn_mfma_f32_16x16x32_f16(af[1][ks], bf, acc1, 0, 0, 0);
      }
      int j = nt * 16 + mrow;
      float Bj = en_s[j];              // ||z||^2 constant per token -> dropped
#pragma unroll
      for (int r = 0; r < 4; ++r) {    // branchless == original if/elif semantics
        float d0 = Bj - 2.f * acc0[r];
        float d1 = Bj - 2.f * acc1[r];
        bool l0 = d0 < m1[0][r];
        m2[0][r] = l0 ? m1[0][r] : fminf(m2[0][r], d0);
        j1[0][r] = l0 ? j : j1[0][r];
        m1[0][r] = l0 ? d0 : m1[0][r];
        bool l1 = d1 < m1[1][r];
        m2[1][r] = l1 ? m1[1][r] : fminf(m2[1][r], d1);
        j1[1][r] = l1 ? j : j1[1][r];
        m1[1][r] = l1 ? d1 : m1[1][r];
      }
    }

    // land the prefetched tile into the other buffer
    if (pf) {
      _Float16* l = (_Float16*)(smem + (buf ^ 1) * 32768 + w * 8192);
#pragma unroll
      for (int i = 0; i < 8; ++i) *(half8*)(l + i * 512 + lane * 8) = st[i];
    }
    __syncthreads();
    buf ^= 1;
  }

  // merge across the 16 lanes of each quad (same tokens, different codes)
#pragma unroll
  for (int d = 1; d < 16; d <<= 1) {
#pragma unroll
    for (int s = 0; s < 2; ++s)
#pragma unroll
      for (int r = 0; r < 4; ++r) {
        float om1 = __shfl_xor(m1[s][r], d, 64);
        float om2 = __shfl_xor(m2[s][r], d, 64);
        int oj = __shfl_xor(j1[s][r], d, 64);
        float hi;
        if (om1 < m1[s][r] || (om1 == m1[s][r] && oj < j1[s][r])) {
          hi = m1[s][r]; m1[s][r] = om1; j1[s][r] = oj;
        } else hi = om1;                 // equal-m1 merges force m2==m1 -> flagged
        m2[s][r] = fminf(m2[s][r], fminf(om2, hi));
      }
  }

  if (mrow == 0) {
#pragma unroll
    for (int s = 0; s < 2; ++s)
#pragma unroll
      for (int r = 0; r < 4; ++r) {
        int tok = w * 32 + s * 16 + quad * 4 + r;
        out_idx[t0 + tok] = (float)j1[s][r];
        if (m2[s][r] - m1[s][r] < TAU) {
          int p = atomicAdd(&loc_cnt, 1);
          loc_tok[p] = tok;
        }
      }
  }
  __syncthreads();
  if (tid == 0) loc_base = (loc_cnt > 0) ? atomicAdd(amb_cnt, loc_cnt) : 0;
  __syncthreads();

  // compact copy-out: one coalesced 1KB zamb row per ambiguous token.
  int cnt = loc_cnt;
  int base = loc_base;
  const float* zcol = z + (size_t)b * ED * S + s0;
  for (int k = 0; k < cnt; ++k) {
    int lt = loc_tok[k];
    int gpos = base + k;
    if (gpos < TOKENS) {
      if (tid == 0) amb_list[gpos] = t0 + lt;
      if (gpos < zcap)
        zamb[(size_t)gpos * ED + tid] = zcol[(size_t)tid * S + lt];
    }
  }
}

// ---------------- ||z||^2 for ambiguous tokens (exact ascending-c chain) ------
// One thread per token; identical fmaf order to the rescan-folded chain, so
// the downstream d = fl(fl(A+B) - 2M) is bit-identical.
__global__ void __launch_bounds__(256)
k_anorm(const float* __restrict__ zamb, const int* __restrict__ amb_cnt,
        float* __restrict__ As, int zcap) {
#pragma clang fp contract(off)
  int n = *amb_cnt;
  if (n > TOKENS) n = TOKENS;
  int lim = n < zcap ? n : zcap;
  for (int i = blockIdx.x * 256 + threadIdx.x; i < lim; i += gridDim.x * 256) {
    const float* zr = zamb + (size_t)i * ED;
    float A = 0.f;
    for (int c = 0; c < ED; c += 4) {
      float4 zv = *(const float4*)(zr + c);
      A = fmaf(zv.x, zv.x, A); A = fmaf(zv.y, zv.y, A);
      A = fmaf(zv.z, zv.z, A); A = fmaf(zv.w, zv.w, A);
    }
    As[i] = A;
  }
}

// ---------------- exact-np rescan: 8 tokens/tile, code range SPLIT x2 ---------
// Work item = (tile, half): block handles 8 tokens x 512 codes, 2 codes/thread
// (j0 = half*512 + tid*2). A loaded precomputed (k_anorm). Cross-block merge:
// order-preserving float->u32 transform packed with code idx into u64,
// atomicMin == lex-(d,j) min == numpy first-index argmin. (-0.0 cannot occur:
// x-y==0 rounds to +0 in RNE, so the transform is tie-exact.)
#define RT 8
__global__ void __launch_bounds__(256)
k_rescan(const float* __restrict__ z, const float* __restrict__ embT,
         const float* __restrict__ en, const int* __restrict__ amb_cnt,
         const int* __restrict__ amb_list, const float* __restrict__ zamb,
         const float* __restrict__ As, int zcap,
         unsigned long long* __restrict__ packed) {
#pragma clang fp contract(off)
  __shared__ float zs[RT][256];
  __shared__ float As_s[RT];
  __shared__ float m1s[RT][256];
  __shared__ int   jms[RT][256];
  int n = *amb_cnt;
  if (n > TOKENS) n = TOKENS;
  int nwork = ((n + RT - 1) / RT) * 2;
  int tid = threadIdx.x;

  for (int idx = blockIdx.x; idx < nwork; idx += gridDim.x) {
    int tile = idx >> 1;
    int half = idx & 1;
    int j0 = half * 512 + tid * 2;
    __syncthreads();                       // protect zs/m1s reuse across tiles
#pragma unroll
    for (int it = 0; it < RT; ++it) {
      int i = tile * RT + it;
      int li = i < n ? i : n - 1;
      if (li < zcap) {
        zs[it][tid] = zamb[(size_t)li * ED + tid];       // coalesced row
      } else {
        int t = amb_list[li];
        int b = t >> 15, s = t & 32767;
        zs[it][tid] = z[(size_t)b * ED * S + (size_t)tid * S + s];
      }
    }
    if (tid < RT) {
      int i = tile * RT + tid;
      int li = i < n ? i : n - 1;
      As_s[tid] = li < zcap ? As[li] : 0.f;
    }
    __syncthreads();

    float A[RT];
#pragma unroll
    for (int it = 0; it < RT; ++it) {
      int i = tile * RT + it;
      int li = i < n ? i : n - 1;
      if (li < zcap) {
        A[it] = As_s[it];
      } else {                             // overflow fallback: exact inline chain
        float Av = 0.f;
        for (int c = 0; c < ED; c += 4) {
          float4 zv = *(const float4*)(&zs[it][c]);
          Av = fmaf(zv.x, zv.x, Av); Av = fmaf(zv.y, zv.y, Av);
          Av = fmaf(zv.z, zv.z, Av); Av = fmaf(zv.w, zv.w, Av);
        }
        A[it] = Av;
      }
    }

    float a0[RT], a1[RT];
#pragma unroll
    for (int tk = 0; tk < RT; ++tk) { a0[tk] = 0.f; a1[tk] = 0.f; }
    for (int c = 0; c < ED; c += 4) {
      // q{0..3}.x/.y = codes j0/j0+1 at channels c..c+3 (coalesced)
      float2 q0 = *(const float2*)(embT + (size_t)(c + 0) * NE + j0);
      float2 q1 = *(const float2*)(embT + (size_t)(c + 1) * NE + j0);
      float2 q2 = *(const float2*)(embT + (size_t)(c + 2) * NE + j0);
      float2 q3 = *(const float2*)(embT + (size_t)(c + 3) * NE + j0);
#pragma unroll
      for (int tk = 0; tk < RT; ++tk) {
        float4 zv = *(const float4*)(&zs[tk][c]);
        a0[tk] = fmaf(zv.x, q0.x, a0[tk]); a0[tk] = fmaf(zv.y, q1.x, a0[tk]);
        a0[tk] = fmaf(zv.z, q2.x, a0[tk]); a0[tk] = fmaf(zv.w, q3.x, a0[tk]);
        a1[tk] = fmaf(zv.x, q0.y, a1[tk]); a1[tk] = fmaf(zv.y, q1.y, a1[tk]);
        a1[tk] = fmaf(zv.z, q2.y, a1[tk]); a1[tk] = fmaf(zv.w, q3.y, a1[tk]);
      }
    }

    float e0n = en[j0 + 0], e1n = en[j0 + 1];
#pragma unroll
    for (int tk = 0; tk < RT; ++tk) {
      float d0 = (A[tk] + e0n) - 2.f * a0[tk];
      float d1 = (A[tk] + e1n) - 2.f * a1[tk];
      float bm = d0; int bi = j0;
      if (d1 < bm) { bm = d1; bi = j0 + 1; }
      m1s[tk][tid] = bm; jms[tk][tid] = bi;
    }
    __syncthreads();

    for (int off = 128; off > 0; off >>= 1) {
      if (tid < off) {
#pragma unroll
        for (int tk = 0; tk < RT; ++tk) {
          float dv = m1s[tk][tid + off]; int jv = jms[tk][tid + off];
          float dc = m1s[tk][tid];       int jc = jms[tk][tid];
          if (dv < dc || (dv == dc && jv < jc)) {
            m1s[tk][tid] = dv; jms[tk][tid] = jv;
          }
        }
      }
      __syncthreads();
    }

    if (tid < RT) {
      int i = tile * RT + tid;
      if (i < n) {
        uint32_t ub = __float_as_uint(m1s[tid][0]);
        ub = (ub & 0x80000000u) ? ~ub : (ub | 0x80000000u);
        unsigned long long v =
            ((unsigned long long)ub << 32) | (unsigned)jms[tid][0];
        atomicMin(&packed[i], v);
      }
    }
  }
}

// ---------------- decode packed lex-min -> out_idx ----------------
__global__ void __launch_bounds__(256)
k_dec(const int* __restrict__ amb_cnt, const int* __restrict__ amb_list,
      const unsigned long long* __restrict__ packed,
      float* __restrict__ out_idx) {
  int n = *amb_cnt;
  if (n > TOKENS) n = TOKENS;
  for (int i = blockIdx.x * 256 + threadIdx.x; i < n; i += gridDim.x * 256)
    out_idx[amb_list[i]] = (float)(unsigned)(packed[i] & 0xffffffffULL);
}

// ---------------- epilogue: z_q gather + loss + sampled ----------------
__global__ void __launch_bounds__(256)
k_epi(const float* __restrict__ z, const float* __restrict__ emb,
      const float* __restrict__ idxf, float* __restrict__ out_zq,
      float* __restrict__ out_samp, float* __restrict__ out_loss) {
  __shared__ float red[256];
  int tid = threadIdx.x;
  int lane = tid & 63;
  int w = tid >> 6;
  int t0 = blockIdx.x * 64;
  int b = t0 >> 15;
  int s0 = t0 & 32767;

  int jm = (int)idxf[t0 + lane];
  if (w == 0) out_samp[jm] = 1.0f;     // idx < 1024 -> always row 0

  const float* zb = z + ((size_t)b * ED * S) + s0;
  float* zqb = out_zq + ((size_t)b * ED * S) + s0;
  const float* erow = emb + (size_t)jm * ED;
  float lacc = 0.f;
  for (int cc = w; cc < ED; cc += 4) {
    float zq = erow[cc];
    float zv = zb[(size_t)cc * S + lane];
    float df = zq - zv;
    lacc = fmaf(df, df, lacc);
    zqb[(size_t)cc * S + lane] = zq;
  }
  red[tid] = lacc;
  __syncthreads();
  for (int off = 128; off > 0; off >>= 1) {
    if (tid < off) red[tid] += red[tid + off];
    __syncthreads();
  }
  if (tid == 0)
    atomicAdd(out_loss, red[0] * (1.2f / 16777216.0f));  // (1+BETA)*mean
}

// ---------------- codebook self-distance: LDS-tiled fp32 GEMM ----------------
__global__ void __launch_bounds__(256)
k_cd(const float* __restrict__ emb, const float* __restrict__ en,
     float* __restrict__ cd) {
  __shared__ float At[64 * 260];
  __shared__ float Bt[64 * 260];
  int bi = blockIdx.x >> 4, bj = blockIdx.x & 15;
  int tid = threadIdx.x;
  const float4* ev = (const float4*)emb;
  for (int idx = tid; idx < 64 * 64; idx += 256) {
    int row = idx >> 6, c4 = idx & 63;
    *(float4*)(&At[row * 260 + c4 * 4]) = ev[(size_t)(bi * 64 + row) * 64 + c4];
    *(float4*)(&Bt[row * 260 + c4 * 4]) = ev[(size_t)(bj * 64 + row) * 64 + c4];
  }
  __syncthreads();
  int ti = tid & 15, tj = tid >> 4;
  float acc[4][4] = {};
  for (int c = 0; c < ED; c += 4) {
    float4 a[4], bq[4];
#pragma unroll
    for (int p = 0; p < 4; ++p) a[p] = *(const float4*)(&At[(ti * 4 + p) * 260 + c]);
#pragma unroll
    for (int q = 0; q < 4; ++q) bq[q] = *(const float4*)(&Bt[(tj * 4 + q) * 260 + c]);
#pragma unroll
    for (int p = 0; p < 4; ++p)
#pragma unroll
      for (int q = 0; q < 4; ++q) {
        acc[p][q] = fmaf(a[p].x, bq[q].x, acc[p][q]);
        acc[p][q] = fmaf(a[p].y, bq[q].y, acc[p][q]);
        acc[p][q] = fmaf(a[p].z, bq[q].z, acc[p][q]);
        acc[p][q] = fmaf(a[p].w, bq[q].w, acc[p][q]);
      }
  }
#pragma unroll
  for (int p = 0; p < 4; ++p)
#pragma unroll
    for (int q = 0; q < 4; ++q) {
      int i = bi * 64 + ti * 4 + p;
      int j = bj * 64 + tj * 4 + q;
      cd[(size_t)i * NE + j] = (en[i] + en[j]) - 2.f * acc[p][q];
    }
}

// ---------------- per-column 2nd smallest -> mean ----------------
__global__ void __launch_bounds__(256)
k_colstats(const float* __restrict__ cd, float* __restrict__ out_md) {
  int tid = threadIdx.x;
  int j = blockIdx.x * 16 + (tid & 15);
  int chunk = tid >> 4;
  float m1 = 3.4e38f, m2 = 3.4e38f;
  int r0 = chunk * 64;
  for (int r = r0; r < r0 + 64; ++r) {
    float v = cd[(size_t)r * NE + j];
    if (v < m1) { m2 = m1; m1 = v; }
    else if (v < m2) { m2 = v; }
  }
  __shared__ float s1[256], s2[256];
  s1[tid] = m1; s2[tid] = m2;
  __syncthreads();
  if (chunk == 0) {
    for (int cc = 1; cc < 16; ++cc) {
      float n1 = s1[cc * 16 + tid], n2 = s2[cc * 16 + tid];
      float lo = fminf(m1, n1);
      float hi = fmaxf(m1, n1);
      m2 = fminf(hi, fminf(m2, n2));
      m1 = lo;
    }
    atomicAdd(out_md, m2 * (1.0f / 1024.0f));
  }
}

// ---------------- per-row variance (ddof=1) -> mean ----------------
__global__ void k_var(const float* __restrict__ cd, float* __restrict__ out_mv) {
  int i = blockIdx.x;
  int tid = threadIdx.x;
  const float* row = cd + (size_t)i * NE;
  __shared__ float red[256];
  float s = row[tid] + row[tid + 256] + row[tid + 512] + row[tid + 768];
  red[tid] = s;
  __syncthreads();
  for (int off = 128; off > 0; off >>= 1) {
    if (tid < off) red[tid] += red[tid + off];
    __syncthreads();
  }
  float mean = red[0] * (1.0f / 1024.0f);
  __syncthreads();
  float d0 = row[tid] - mean, d1 = row[tid + 256] - mean,
        d2 = row[tid + 512] - mean, d3 = row[tid + 768] - mean;
  red[tid] = d0 * d0 + d1 * d1 + d2 * d2 + d3 * d3;
  __syncthreads();
  for (int off = 128; off > 0; off >>= 1) {
    if (tid < off) red[tid] += red[tid + off];
    __syncthreads();
  }
  if (tid == 0)
    atomicAdd(out_mv, red[0] * (1.0f / 1023.0f) * (1.0f / 1024.0f));
}

extern "C" void kernel_launch(void* const* d_in, const int* in_sizes, int n_in,
                              void* d_out, int out_size, void* d_ws, size_t ws_size,
                              hipStream_t stream) {
  const float* z   = (const float*)d_in[0];
  const float* emb = (const float*)d_in[1];
  float* out = (float*)d_out;

  float* cd = (float*)d_ws;                       // 4 MiB
  float* en = cd + (size_t)NE * NE;               // 4 KiB
  _Float16* embf = (_Float16*)(en + NE);          // 512 KiB fragment-ordered fp16
  int* amb_cnt = (int*)(embf + (size_t)NE * ED);
  int* amb_list = amb_cnt + 16;                   // TOKENS ints (256 KiB)
  unsigned long long* packed =
      (unsigned long long*)(amb_list + TOKENS);   // 512 KiB lex-min cells
  float* As = (float*)(packed + TOKENS);          // 64 KiB precomputed ||z||^2
  float* embT = As + ZCAP_MAX;                    // 1 MiB transposed codebook
  float* zamb = embT + (size_t)ED * NE;           // compacted z rows (1KB each)

  size_t base_bytes = (size_t)((char*)zamb - (char*)d_ws);
  int zcap = 0;
  if (ws_size > base_bytes) {
    size_t rows = (ws_size - base_bytes) / ((size_t)ED * sizeof(float));
    zcap = rows > (size_t)ZCAP_MAX ? ZCAP_MAX : (int)rows;
  }

  hipMemsetAsync(out + OFF_LOSS, 0,
                 (size_t)(out_size - OFF_LOSS) * sizeof(float), stream);
  hipMemsetAsync(amb_cnt, 0, sizeof(int), stream);
  hipMemsetAsync(packed, 0xFF, (size_t)TOKENS * 8, stream);  // u64 max

  k_enorm<<<NE / 256, 256, 0, stream>>>(emb, en);
  k_cvt<<<64, 512, 0, stream>>>(emb, embf);
  k_tr<<<256, 256, 0, stream>>>(emb, embT);
  k_filter<<<TOKENS / 128, 256, 0, stream>>>(z, embf, en, out + OFF_IDX,
                                             amb_cnt, amb_list, zamb, zcap);
  k_anorm<<<64, 256, 0, stream>>>(zamb, amb_cnt, As, zcap);
  k_rescan<<<4096, 256, 0, stream>>>(z, embT, en, amb_cnt, amb_list,
                                     zamb, As, zcap, packed);
  k_dec<<<64, 256, 0, stream>>>(amb_cnt, amb_list, packed, out + OFF_IDX);
  k_epi<<<TOKENS / 64, 256, 0, stream>>>(z, emb, out + OFF_IDX,
                                         out, out + OFF_SAMP, out + OFF_LOSS);
  k_cd<<<256, 256, 0, stream>>>(emb, en, cd);
  k_colstats<<<64, 256, 0, stream>>>(cd, out + OFF_MD);
  k_var<<<NE, 256, 0, stream>>>(cd, out + OFF_MV);
}

// Round 8
// 281.403 us; speedup vs baseline: 1.8438x; 1.1656x over previous
//
#include <hip/hip_runtime.h>
#include <stdint.h>

#define NE   1024
#define ED   256
#define NB   2
#define S    32768            // 32*32*32
#define TOKENS (NB*S)         // 65536

#define OFF_LOSS 16777216
#define OFF_IDX  16777217
#define OFF_SAMP 16842753
#define OFF_MD   16844801
#define OFF_MV   16844802

#define TAU 2.5e-4f           // fp16-filter ambiguity margin (~6 sigma of 3e-5 err)
#define ZCAP_MAX 16384        // max compacted z rows (16.8 MiB)

typedef _Float16 half8 __attribute__((ext_vector_type(8)));
typedef float floatx4 __attribute__((ext_vector_type(4)));

// ---------------- fused prep: enorm + cvt + tr + inits (one launch) ----------
// blocks   0..3   : codebook norms (bitwise numpy pairwise sum)
// blocks   4..131 : emb -> fragment-ordered fp16 embf
// blocks 132..387 : emb -> transposed fp32 embT[c][j]
// blocks 388..643 : packed[] = u64max, amb_cnt = 0
__global__ void __launch_bounds__(256)
k_prep(const float* __restrict__ emb, float* __restrict__ en,
       _Float16* __restrict__ embf, float* __restrict__ embT,
       unsigned long long* __restrict__ packed, int* __restrict__ amb_cnt) {
  __shared__ float t[32][33];
  int blk = blockIdx.x, tid = threadIdx.x;
  if (blk < 4) {
#pragma clang fp contract(off)
    int j = blk * 256 + tid;
    const float* e = emb + (size_t)j * ED;
    float halves[2];
    for (int h = 0; h < 2; ++h) {
      const float* a = e + h * 128;
      float r[8];
      for (int k = 0; k < 8; ++k) r[k] = a[k] * a[k];
      for (int i = 8; i < 128; i += 8)
        for (int k = 0; k < 8; ++k) r[k] += a[i + k] * a[i + k];
      halves[h] = ((r[0] + r[1]) + (r[2] + r[3])) + ((r[4] + r[5]) + (r[6] + r[7]));
    }
    en[j] = halves[0] + halves[1];
  } else if (blk < 132) {
    int g = (blk - 4) * 256 + tid;     // [0, 32768)
    int lane = g & 63;
    int ks = (g >> 6) & 7;
    int nt = g >> 9;
    int n = nt * 16 + (lane & 15);
    int k0 = ks * 32 + (lane >> 4) * 8;
    const float* src = emb + (size_t)n * ED + k0;
    half8 v;
#pragma unroll
    for (int j = 0; j < 8; ++j) v[j] = (_Float16)src[j];
    *(half8*)(embf + ((size_t)((nt * 8 + ks) * 64 + lane)) * 8) = v;
  } else if (blk < 388) {
    int bidx = blk - 132;
    int bj = bidx >> 3;                // 0..31: code tile
    int bc = bidx & 7;                 // 0..7 : channel tile
    int tx = tid & 31, ty = tid >> 5;
    int j0 = bj * 32, c0 = bc * 32;
#pragma unroll
    for (int k = 0; k < 4; ++k)
      t[ty + 8 * k][tx] = emb[(size_t)(j0 + ty + 8 * k) * ED + c0 + tx];
    __syncthreads();
#pragma unroll
    for (int k = 0; k < 4; ++k)
      embT[(size_t)(c0 + ty + 8 * k) * NE + j0 + tx] = t[tx][ty + 8 * k];
  } else {
    int idx = (blk - 388) * 256 + tid; // [0, 65536)
    packed[idx] = 0xFFFFFFFFFFFFFFFFULL;
    if (blk == 388 && tid == 0) *amb_cnt = 0;
  }
}

// ---------------- MFMA filter: approx argmin + top-2 ambiguity ----------------
// 128 tokens/block, 256 thr = 4 waves. B-stream LDS-shared; float4 z staging.
// (unchanged from round 7 -- pinned at the stride-S z-read wall ~1 TB/s)
__global__ void __launch_bounds__(256)
k_filter(const float* __restrict__ z, const _Float16* __restrict__ embf,
         const float* __restrict__ en, float* __restrict__ out_idx,
         int* __restrict__ amb_cnt, int* __restrict__ amb_list,
         float* __restrict__ zamb, int zcap) {
  __shared__ __align__(16) char smem[128 * 264 * 2];  // zA region, reused as B dbuf
  __shared__ float en_s[NE];
  __shared__ int loc_cnt, loc_base;
  __shared__ int loc_tok[128];
  _Float16* zA = (_Float16*)smem;      // [tok][264] during phase 1

  int tid = threadIdx.x;
  int lane = tid & 63;
  int w = tid >> 6;
  int mrow = lane & 15;
  int quad = lane >> 4;
  int t0 = blockIdx.x * 128;
  int b = t0 >> 15;                    // 32768 % 128 == 0: no straddle
  int s0 = t0 & 32767;

  if (tid == 0) loc_cnt = 0;
  for (int i = tid; i < NE; i += 256) en_s[i] = en[i];

  {  // stage z tile -> fp16 LDS: float4 along s (4 tokens x 1 channel per load)
    int tok4 = (tid & 31) * 4;         // token group base
    int cg = tid >> 5;                 // 0..7: channel group of 32
    const float* zb = z + (size_t)b * ED * S + s0 + tok4;
    for (int cc = 0; cc < 32; cc += 8) {
      float4 v[8];
#pragma unroll
      for (int u = 0; u < 8; ++u)
        v[u] = *(const float4*)(zb + (size_t)(cg * 32 + cc + u) * S);
#pragma unroll
      for (int u = 0; u < 8; u += 2) {
        int c = cg * 32 + cc + u;
#pragma unroll
        for (int k = 0; k < 4; ++k) {
          union { _Float16 h[2]; uint32_t u32; } p;
          p.h[0] = (_Float16)((&v[u].x)[k]);
          p.h[1] = (_Float16)((&v[u + 1].x)[k]);
          *(uint32_t*)(&zA[(tok4 + k) * 264 + c]) = p.u32;
        }
      }
    }
  }
  __syncthreads();

  // A-frags register-resident: af[stripe][kstep]
  half8 af[2][8];
#pragma unroll
  for (int s = 0; s < 2; ++s)
#pragma unroll
    for (int ks = 0; ks < 8; ++ks)
      af[s][ks] = *(const half8*)(&zA[(w * 32 + s * 16 + mrow) * 264 + ks * 32 + quad * 8]);

  __syncthreads();                     // zA dead -> region becomes B dbuf

  float m1[2][4], m2[2][4];
  int j1[2][4];
#pragma unroll
  for (int s = 0; s < 2; ++s)
#pragma unroll
    for (int r = 0; r < 4; ++r) { m1[s][r] = 3.4e38f; m2[s][r] = 3.4e38f; j1[s][r] = 0; }

  // prologue: stage chunk 0 (tiles 0..3; wave w stages tile w = 8 KB)
  {
    const half8* g = (const half8*)embf + (size_t)w * 512 + lane;
    half8 st[8];
#pragma unroll
    for (int i = 0; i < 8; ++i) st[i] = g[i * 64];
    _Float16* l = (_Float16*)(smem + w * 8192);
#pragma unroll
    for (int i = 0; i < 8; ++i) *(half8*)(l + i * 512 + lane * 8) = st[i];
  }
  __syncthreads();

  int buf = 0;
  for (int chunk = 0; chunk < 16; ++chunk) {
    // T14: issue next chunk's global loads BEFORE compute (hide L2 latency)
    half8 st[8];
    bool pf = chunk < 15;
    if (pf) {
      const half8* g = (const half8*)embf + ((size_t)(chunk + 1) * 4 + w) * 512 + lane;
#pragma unroll
      for (int i = 0; i < 8; ++i) st[i] = g[i * 64];
    }

    // compute 4 tiles from buf (B values bit-identical to the L2-direct path)
#pragma unroll
    for (int ntl = 0; ntl < 4; ++ntl) {
      int nt = chunk * 4 + ntl;
      const half8* pb = (const half8*)(smem + buf * 32768 + ntl * 8192) + lane;
      floatx4 acc0 = {0.f, 0.f, 0.f, 0.f}, acc1 = {0.f, 0.f, 0.f, 0.f};
#pragma unroll
      for (int ks = 0; ks < 8; ++ks) {
        half8 bf = pb[ks * 64];
        acc0 = __builtin_amdgcn_mfma_f32_16x16x32_f16(af[0][ks], bf, acc0, 0, 0, 0);
        acc1 = __builtin_amdgcn_mfma_f32_16x16x32_f16(af[1][ks], bf, acc1, 0, 0, 0);
      }
      int j = nt * 16 + mrow;
      float Bj = en_s[j];              // ||z||^2 constant per token -> dropped
#pragma unroll
      for (int r = 0; r < 4; ++r) {    // branchless == original if/elif semantics
        float d0 = Bj - 2.f * acc0[r];
        float d1 = Bj - 2.f * acc1[r];
        bool l0 = d0 < m1[0][r];
        m2[0][r] = l0 ? m1[0][r] : fminf(m2[0][r], d0);
        j1[0][r] = l0 ? j : j1[0][r];
        m1[0][r] = l0 ? d0 : m1[0][r];
        bool l1 = d1 < m1[1][r];
        m2[1][r] = l1 ? m1[1][r] : fminf(m2[1][r], d1);
        j1[1][r] = l1 ? j : j1[1][r];
        m1[1][r] = l1 ? d1 : m1[1][r];
      }
    }

    // land the prefetched tile into the other buffer
    if (pf) {
      _Float16* l = (_Float16*)(smem + (buf ^ 1) * 32768 + w * 8192);
#pragma unroll
      for (int i = 0; i < 8; ++i) *(half8*)(l + i * 512 + lane * 8) = st[i];
    }
    __syncthreads();
    buf ^= 1;
  }

  // merge across the 16 lanes of each quad (same tokens, different codes)
#pragma unroll
  for (int d = 1; d < 16; d <<= 1) {
#pragma unroll
    for (int s = 0; s < 2; ++s)
#pragma unroll
      for (int r = 0; r < 4; ++r) {
        float om1 = __shfl_xor(m1[s][r], d, 64);
        float om2 = __shfl_xor(m2[s][r], d, 64);
        int oj = __shfl_xor(j1[s][r], d, 64);
        float hi;
        if (om1 < m1[s][r] || (om1 == m1[s][r] && oj < j1[s][r])) {
          hi = m1[s][r]; m1[s][r] = om1; j1[s][r] = oj;
        } else hi = om1;                 // equal-m1 merges force m2==m1 -> flagged
        m2[s][r] = fminf(m2[s][r], fminf(om2, hi));
      }
  }

  if (mrow == 0) {
#pragma unroll
    for (int s = 0; s < 2; ++s)
#pragma unroll
      for (int r = 0; r < 4; ++r) {
        int tok = w * 32 + s * 16 + quad * 4 + r;
        out_idx[t0 + tok] = (float)j1[s][r];
        if (m2[s][r] - m1[s][r] < TAU) {
          int p = atomicAdd(&loc_cnt, 1);
          loc_tok[p] = tok;
        }
      }
  }
  __syncthreads();
  if (tid == 0) loc_base = (loc_cnt > 0) ? atomicAdd(amb_cnt, loc_cnt) : 0;
  __syncthreads();

  // compact copy-out: one coalesced 1KB zamb row per ambiguous token.
  int cnt = loc_cnt;
  int base = loc_base;
  const float* zcol = z + (size_t)b * ED * S + s0;
  for (int k = 0; k < cnt; ++k) {
    int lt = loc_tok[k];
    int gpos = base + k;
    if (gpos < TOKENS) {
      if (tid == 0) amb_list[gpos] = t0 + lt;
      if (gpos < zcap)
        zamb[(size_t)gpos * ED + tid] = zcol[(size_t)tid * S + lt];
    }
  }
}

// ---------------- exact-np rescan: 8 tokens/tile, code range SPLIT x2 ---------
// Work item = (tile, half): block handles 8 tokens x 512 codes, 2 codes/thread.
// A (= ||z||^2) computed per tile by 8 threads running the IDENTICAL
// ascending-c fmaf chain from the LDS copy of the exact fp32 z row (replaces
// the k_anorm launch; bit-identical values). Cross-block merge via
// order-preserving u32 transform packed with code idx -> u64 atomicMin
// (== lex-(d,j) min == numpy first-index argmin; -0.0 cannot occur in RNE).
#define RT 8
__global__ void __launch_bounds__(256)
k_rescan(const float* __restrict__ z, const float* __restrict__ embT,
         const float* __restrict__ en, const int* __restrict__ amb_cnt,
         const int* __restrict__ amb_list, const float* __restrict__ zamb,
         int zcap, unsigned long long* __restrict__ packed) {
#pragma clang fp contract(off)
  __shared__ float zs[RT][256];
  __shared__ float As_s[RT];
  __shared__ float m1s[RT][256];
  __shared__ int   jms[RT][256];
  int n = *amb_cnt;
  if (n > TOKENS) n = TOKENS;
  int nwork = ((n + RT - 1) / RT) * 2;
  int tid = threadIdx.x;

  for (int idx = blockIdx.x; idx < nwork; idx += gridDim.x) {
    int tile = idx >> 1;
    int half = idx & 1;
    int j0 = half * 512 + tid * 2;
    __syncthreads();                       // protect zs/m1s reuse across tiles
#pragma unroll
    for (int it = 0; it < RT; ++it) {
      int i = tile * RT + it;
      int li = i < n ? i : n - 1;
      if (li < zcap) {
        zs[it][tid] = zamb[(size_t)li * ED + tid];       // coalesced row
      } else {
        int t = amb_list[li];
        int b = t >> 15, s = t & 32767;
        zs[it][tid] = z[(size_t)b * ED * S + (size_t)tid * S + s];
      }
    }
    __syncthreads();
    if (tid < RT) {                        // exact ascending-c ||z||^2 chain
      float Av = 0.f;
      for (int c = 0; c < ED; c += 4) {
        float4 zv = *(const float4*)(&zs[tid][c]);
        Av = fmaf(zv.x, zv.x, Av); Av = fmaf(zv.y, zv.y, Av);
        Av = fmaf(zv.z, zv.z, Av); Av = fmaf(zv.w, zv.w, Av);
      }
      As_s[tid] = Av;
    }
    __syncthreads();

    float A[RT];
#pragma unroll
    for (int it = 0; it < RT; ++it) A[it] = As_s[it];

    float a0[RT], a1[RT];
#pragma unroll
    for (int tk = 0; tk < RT; ++tk) { a0[tk] = 0.f; a1[tk] = 0.f; }
    for (int c = 0; c < ED; c += 4) {
      // q{0..3}.x/.y = codes j0/j0+1 at channels c..c+3 (coalesced)
      float2 q0 = *(const float2*)(embT + (size_t)(c + 0) * NE + j0);
      float2 q1 = *(const float2*)(embT + (size_t)(c + 1) * NE + j0);
      float2 q2 = *(const float2*)(embT + (size_t)(c + 2) * NE + j0);
      float2 q3 = *(const float2*)(embT + (size_t)(c + 3) * NE + j0);
#pragma unroll
      for (int tk = 0; tk < RT; ++tk) {
        float4 zv = *(const float4*)(&zs[tk][c]);
        a0[tk] = fmaf(zv.x, q0.x, a0[tk]); a0[tk] = fmaf(zv.y, q1.x, a0[tk]);
        a0[tk] = fmaf(zv.z, q2.x, a0[tk]); a0[tk] = fmaf(zv.w, q3.x, a0[tk]);
        a1[tk] = fmaf(zv.x, q0.y, a1[tk]); a1[tk] = fmaf(zv.y, q1.y, a1[tk]);
        a1[tk] = fmaf(zv.z, q2.y, a1[tk]); a1[tk] = fmaf(zv.w, q3.y, a1[tk]);
      }
    }

    float e0n = en[j0 + 0], e1n = en[j0 + 1];
#pragma unroll
    for (int tk = 0; tk < RT; ++tk) {
      float d0 = (A[tk] + e0n) - 2.f * a0[tk];
      float d1 = (A[tk] + e1n) - 2.f * a1[tk];
      float bm = d0; int bi = j0;
      if (d1 < bm) { bm = d1; bi = j0 + 1; }
      m1s[tk][tid] = bm; jms[tk][tid] = bi;
    }
    __syncthreads();

    for (int off = 128; off > 0; off >>= 1) {
      if (tid < off) {
#pragma unroll
        for (int tk = 0; tk < RT; ++tk) {
          float dv = m1s[tk][tid + off]; int jv = jms[tk][tid + off];
          float dc = m1s[tk][tid];       int jc = jms[tk][tid];
          if (dv < dc || (dv == dc && jv < jc)) {
            m1s[tk][tid] = dv; jms[tk][tid] = jv;
          }
        }
      }
      __syncthreads();
    }

    if (tid < RT) {
      int i = tile * RT + tid;
      if (i < n) {
        uint32_t ub = __float_as_uint(m1s[tid][0]);
        ub = (ub & 0x80000000u) ? ~ub : (ub | 0x80000000u);
        unsigned long long v =
            ((unsigned long long)ub << 32) | (unsigned)jms[tid][0];
        atomicMin(&packed[i], v);
      }
    }
  }
}

// ---------------- decode packed lex-min -> out_idx ----------------
__global__ void __launch_bounds__(256)
k_dec(const int* __restrict__ amb_cnt, const int* __restrict__ amb_list,
      const unsigned long long* __restrict__ packed,
      float* __restrict__ out_idx) {
  int n = *amb_cnt;
  if (n > TOKENS) n = TOKENS;
  for (int i = blockIdx.x * 256 + threadIdx.x; i < n; i += gridDim.x * 256)
    out_idx[amb_list[i]] = (float)(unsigned)(packed[i] & 0xffffffffULL);
}

// ---------------- epilogue: z_q gather + loss + sampled ----------------
// NEW: 256 tokens/block, 512 thr; thread owns 4 consecutive tokens x 32
// channels. z read and zq write are float4 along s -> 64 lanes x 16B = 1KB
// contiguous per wave instruction (vs 256B scalar before). Loss partials keep
// 32-length per-token fmaf chains; block tree + atomic merge as before.
__global__ void __launch_bounds__(512)
k_epi(const float* __restrict__ z, const float* __restrict__ emb,
      const float* __restrict__ idxf, float* __restrict__ out_zq,
      float* __restrict__ out_samp, float* __restrict__ out_loss) {
  __shared__ float red[512];
  int tid = threadIdx.x;
  int tg = tid & 63;                   // token quad id
  int w = tid >> 6;                    // 0..7: channel group of 32
  int t0 = blockIdx.x * 256;
  int b = t0 >> 15;                    // 32768 % 256 == 0: no straddle
  int s0 = t0 & 32767;
  int tok4 = tg * 4;

  int jm0 = (int)idxf[t0 + tok4 + 0];
  int jm1 = (int)idxf[t0 + tok4 + 1];
  int jm2 = (int)idxf[t0 + tok4 + 2];
  int jm3 = (int)idxf[t0 + tok4 + 3];
  if (w == 0) {                        // idx < 1024 -> always row 0
    out_samp[jm0] = 1.0f; out_samp[jm1] = 1.0f;
    out_samp[jm2] = 1.0f; out_samp[jm3] = 1.0f;
  }

  const float* zb = z + (size_t)b * ED * S + s0 + tok4;
  float* zqb = out_zq + (size_t)b * ED * S + s0 + tok4;
  const float* e0r = emb + (size_t)jm0 * ED;
  const float* e1r = emb + (size_t)jm1 * ED;
  const float* e2r = emb + (size_t)jm2 * ED;
  const float* e3r = emb + (size_t)jm3 * ED;
  float l0 = 0.f, l1 = 0.f, l2 = 0.f, l3 = 0.f;
  for (int i = 0; i < 32; ++i) {
    int c = w * 32 + i;
    float4 zv = *(const float4*)(zb + (size_t)c * S);
    float e0 = e0r[c], e1 = e1r[c], e2 = e2r[c], e3 = e3r[c];
    float4 q; q.x = e0; q.y = e1; q.z = e2; q.w = e3;
    *(float4*)(zqb + (size_t)c * S) = q;
    float d0 = e0 - zv.x, d1 = e1 - zv.y, d2 = e2 - zv.z, d3 = e3 - zv.w;
    l0 = fmaf(d0, d0, l0); l1 = fmaf(d1, d1, l1);
    l2 = fmaf(d2, d2, l2); l3 = fmaf(d3, d3, l3);
  }
  red[tid] = (l0 + l1) + (l2 + l3);
  __syncthreads();
  for (int off = 256; off > 0; off >>= 1) {
    if (tid < off) red[tid] += red[tid + off];
    __syncthreads();
  }
  if (tid == 0)
    atomicAdd(out_loss, red[0] * (1.2f / 16777216.0f));  // (1+BETA)*mean
}

// ---------------- codebook self-distance: LDS-tiled fp32 GEMM ----------------
__global__ void __launch_bounds__(256)
k_cd(const float* __restrict__ emb, const float* __restrict__ en,
     float* __restrict__ cd) {
  __shared__ float At[64 * 260];
  __shared__ float Bt[64 * 260];
  int bi = blockIdx.x >> 4, bj = blockIdx.x & 15;
  int tid = threadIdx.x;
  const float4* ev = (const float4*)emb;
  for (int idx = tid; idx < 64 * 64; idx += 256) {
    int row = idx >> 6, c4 = idx & 63;
    *(float4*)(&At[row * 260 + c4 * 4]) = ev[(size_t)(bi * 64 + row) * 64 + c4];
    *(float4*)(&Bt[row * 260 + c4 * 4]) = ev[(size_t)(bj * 64 + row) * 64 + c4];
  }
  __syncthreads();
  int ti = tid & 15, tj = tid >> 4;
  float acc[4][4] = {};
  for (int c = 0; c < ED; c += 4) {
    float4 a[4], bq[4];
#pragma unroll
    for (int p = 0; p < 4; ++p) a[p] = *(const float4*)(&At[(ti * 4 + p) * 260 + c]);
#pragma unroll
    for (int q = 0; q < 4; ++q) bq[q] = *(const float4*)(&Bt[(tj * 4 + q) * 260 + c]);
#pragma unroll
    for (int p = 0; p < 4; ++p)
#pragma unroll
      for (int q = 0; q < 4; ++q) {
        acc[p][q] = fmaf(a[p].x, bq[q].x, acc[p][q]);
        acc[p][q] = fmaf(a[p].y, bq[q].y, acc[p][q]);
        acc[p][q] = fmaf(a[p].z, bq[q].z, acc[p][q]);
        acc[p][q] = fmaf(a[p].w, bq[q].w, acc[p][q]);
      }
  }
#pragma unroll
  for (int p = 0; p < 4; ++p)
#pragma unroll
    for (int q = 0; q < 4; ++q) {
      int i = bi * 64 + ti * 4 + p;
      int j = bj * 64 + tj * 4 + q;
      cd[(size_t)i * NE + j] = (en[i] + en[j]) - 2.f * acc[p][q];
    }
}

// ---------------- fused cd stats: colstats (blocks 0..63) + var (64..1087) ----
__global__ void __launch_bounds__(256)
k_cdpost(const float* __restrict__ cd, float* __restrict__ out_md,
         float* __restrict__ out_mv) {
  __shared__ float s1[256], s2[256];
  __shared__ float red[256];
  int blk = blockIdx.x, tid = threadIdx.x;
  if (blk < 64) {
    int j = blk * 16 + (tid & 15);
    int chunk = tid >> 4;
    float m1 = 3.4e38f, m2 = 3.4e38f;
    int r0 = chunk * 64;
    for (int r = r0; r < r0 + 64; ++r) {
      float v = cd[(size_t)r * NE + j];
      if (v < m1) { m2 = m1; m1 = v; }
      else if (v < m2) { m2 = v; }
    }
    s1[tid] = m1; s2[tid] = m2;
    __syncthreads();
    if (chunk == 0) {
      for (int cc = 1; cc < 16; ++cc) {
        float n1 = s1[cc * 16 + tid], n2 = s2[cc * 16 + tid];
        float lo = fminf(m1, n1);
        float hi = fmaxf(m1, n1);
        m2 = fminf(hi, fminf(m2, n2));
        m1 = lo;
      }
      atomicAdd(out_md, m2 * (1.0f / 1024.0f));
    }
  } else {
    int i = blk - 64;
    const float* row = cd + (size_t)i * NE;
    float s = row[tid] + row[tid + 256] + row[tid + 512] + row[tid + 768];
    red[tid] = s;
    __syncthreads();
    for (int off = 128; off > 0; off >>= 1) {
      if (tid < off) red[tid] += red[tid + off];
      __syncthreads();
    }
    float mean = red[0] * (1.0f / 1024.0f);
    __syncthreads();
    float d0 = row[tid] - mean, d1 = row[tid + 256] - mean,
          d2 = row[tid + 512] - mean, d3 = row[tid + 768] - mean;
    red[tid] = d0 * d0 + d1 * d1 + d2 * d2 + d3 * d3;
    __syncthreads();
    for (int off = 128; off > 0; off >>= 1) {
      if (tid < off) red[tid] += red[tid + off];
      __syncthreads();
    }
    if (tid == 0)
      atomicAdd(out_mv, red[0] * (1.0f / 1023.0f) * (1.0f / 1024.0f));
  }
}

extern "C" void kernel_launch(void* const* d_in, const int* in_sizes, int n_in,
                              void* d_out, int out_size, void* d_ws, size_t ws_size,
                              hipStream_t stream) {
  const float* z   = (const float*)d_in[0];
  const float* emb = (const float*)d_in[1];
  float* out = (float*)d_out;

  float* cd = (float*)d_ws;                       // 4 MiB
  float* en = cd + (size_t)NE * NE;               // 4 KiB
  _Float16* embf = (_Float16*)(en + NE);          // 512 KiB fragment-ordered fp16
  int* amb_cnt = (int*)(embf + (size_t)NE * ED);
  int* amb_list = amb_cnt + 16;                   // TOKENS ints (256 KiB)
  unsigned long long* packed =
      (unsigned long long*)(amb_list + TOKENS);   // 512 KiB lex-min cells
  float* embT = (float*)(packed + TOKENS);        // 1 MiB transposed codebook
  float* zamb = embT + (size_t)ED * NE;           // compacted z rows (1KB each)

  size_t base_bytes = (size_t)((char*)zamb - (char*)d_ws);
  int zcap = 0;
  if (ws_size > base_bytes) {
    size_t rows = (ws_size - base_bytes) / ((size_t)ED * sizeof(float));
    zcap = rows > (size_t)ZCAP_MAX ? ZCAP_MAX : (int)rows;
  }

  hipMemsetAsync(out + OFF_LOSS, 0,
                 (size_t)(out_size - OFF_LOSS) * sizeof(float), stream);

  k_prep<<<644, 256, 0, stream>>>(emb, en, embf, embT, packed, amb_cnt);
  k_filter<<<TOKENS / 128, 256, 0, stream>>>(z, embf, en, out + OFF_IDX,
                                             amb_cnt, amb_list, zamb, zcap);
  k_rescan<<<4096, 256, 0, stream>>>(z, embT, en, amb_cnt, amb_list,
                                     zamb, zcap, packed);
  k_dec<<<64, 256, 0, stream>>>(amb_cnt, amb_list, packed, out + OFF_IDX);
  k_epi<<<TOKENS / 256, 512, 0, stream>>>(z, emb, out + OFF_IDX,
                                          out, out + OFF_SAMP, out + OFF_LOSS);
  k_cd<<<256, 256, 0, stream>>>(emb, en, cd);
  k_cdpost<<<1088, 256, 0, stream>>>(cd, out + OFF_MD, out + OFF_MV);
}

// Round 9
// 281.130 us; speedup vs baseline: 1.8456x; 1.0010x over previous
//
#include <hip/hip_runtime.h>
#include <stdint.h>

#define NE   1024
#define ED   256
#define NB   2
#define S    32768            // 32*32*32
#define TOKENS (NB*S)         // 65536

#define OFF_LOSS 16777216
#define OFF_IDX  16777217
#define OFF_SAMP 16842753
#define OFF_MD   16844801
#define OFF_MV   16844802

#define TAU 2.5e-4f           // fp16-filter ambiguity margin (~6 sigma of 3e-5 err)
#define ZCAP_MAX 16384        // max compacted z rows (16.8 MiB)

typedef _Float16 half8 __attribute__((ext_vector_type(8)));
typedef float floatx4 __attribute__((ext_vector_type(4)));

// ---------------- fused prep: enorm + cvt + tr + inits (one launch) ----------
// blocks   0..3   : codebook norms (bitwise numpy pairwise sum)
// blocks   4..131 : emb -> fragment-ordered fp16 embf
// blocks 132..387 : emb -> transposed fp32 embT[c][j]
// blocks 388..643 : packed[] = u64max, amb_cnt = 0
__global__ void __launch_bounds__(256)
k_prep(const float* __restrict__ emb, float* __restrict__ en,
       _Float16* __restrict__ embf, float* __restrict__ embT,
       unsigned long long* __restrict__ packed, int* __restrict__ amb_cnt) {
  __shared__ float t[32][33];
  int blk = blockIdx.x, tid = threadIdx.x;
  if (blk < 4) {
#pragma clang fp contract(off)
    int j = blk * 256 + tid;
    const float* e = emb + (size_t)j * ED;
    float halves[2];
    for (int h = 0; h < 2; ++h) {
      const float* a = e + h * 128;
      float r[8];
      for (int k = 0; k < 8; ++k) r[k] = a[k] * a[k];
      for (int i = 8; i < 128; i += 8)
        for (int k = 0; k < 8; ++k) r[k] += a[i + k] * a[i + k];
      halves[h] = ((r[0] + r[1]) + (r[2] + r[3])) + ((r[4] + r[5]) + (r[6] + r[7]));
    }
    en[j] = halves[0] + halves[1];
  } else if (blk < 132) {
    int g = (blk - 4) * 256 + tid;     // [0, 32768)
    int lane = g & 63;
    int ks = (g >> 6) & 7;
    int nt = g >> 9;
    int n = nt * 16 + (lane & 15);
    int k0 = ks * 32 + (lane >> 4) * 8;
    const float* src = emb + (size_t)n * ED + k0;
    half8 v;
#pragma unroll
    for (int j = 0; j < 8; ++j) v[j] = (_Float16)src[j];
    *(half8*)(embf + ((size_t)((nt * 8 + ks) * 64 + lane)) * 8) = v;
  } else if (blk < 388) {
    int bidx = blk - 132;
    int bj = bidx >> 3;                // 0..31: code tile
    int bc = bidx & 7;                 // 0..7 : channel tile
    int tx = tid & 31, ty = tid >> 5;
    int j0 = bj * 32, c0 = bc * 32;
#pragma unroll
    for (int k = 0; k < 4; ++k)
      t[ty + 8 * k][tx] = emb[(size_t)(j0 + ty + 8 * k) * ED + c0 + tx];
    __syncthreads();
#pragma unroll
    for (int k = 0; k < 4; ++k)
      embT[(size_t)(c0 + ty + 8 * k) * NE + j0 + tx] = t[tx][ty + 8 * k];
  } else {
    int idx = (blk - 388) * 256 + tid; // [0, 65536)
    packed[idx] = 0xFFFFFFFFFFFFFFFFULL;
    if (blk == 388 && tid == 0) *amb_cnt = 0;
  }
}

// ---------------- MFMA filter: approx argmin + top-2 ambiguity ----------------
// NEW: 256 tokens/block, 512 thr = 8 waves (wave w owns tokens [w*32,w*32+32)).
// z staging now 1KB contiguous per wave-instruction (64 lanes x float4 along s)
// and 256 blocks instead of 512 -- longer runs / fewer interleaved streams for
// the stride-S sweep that was pinning staging at ~1.6 TB/s. B-stream staged
// through LDS shared by all 8 waves (wave-pair per tile). MFMA values, fragment
// layout, merge, TAU semantics all bit-identical to round 8.
__global__ void __launch_bounds__(512)
k_filter(const float* __restrict__ z, const _Float16* __restrict__ embf,
         const float* __restrict__ en, float* __restrict__ out_idx,
         int* __restrict__ amb_cnt, int* __restrict__ amb_list,
         float* __restrict__ zamb, int zcap) {
  __shared__ __align__(16) char smem[256 * 264 * 2];  // zA; first 64KB reused as B dbuf
  __shared__ float en_s[NE];
  __shared__ int loc_cnt, loc_base;
  __shared__ int loc_tok[256];
  _Float16* zA = (_Float16*)smem;      // [tok][264] during phase 1

  int tid = threadIdx.x;
  int lane = tid & 63;
  int w = tid >> 6;                    // 0..7
  int mrow = lane & 15;
  int quad = lane >> 4;
  int t0 = blockIdx.x * 256;
  int b = t0 >> 15;                    // 32768 % 256 == 0: no straddle
  int s0 = t0 & 32767;

  if (tid == 0) loc_cnt = 0;
  for (int i = tid; i < NE; i += 512) en_s[i] = en[i];

  {  // stage z tile -> fp16 LDS: float4 along s (4 tokens x 1 channel per load)
    int tok4 = (tid & 63) * 4;         // token group base (0..252 step 4)
    int cg = tid >> 6;                 // 0..7: channel group of 32
    const float* zb = z + (size_t)b * ED * S + s0 + tok4;
    for (int cc = 0; cc < 32; cc += 8) {
      float4 v[8];
#pragma unroll
      for (int u = 0; u < 8; ++u)
        v[u] = *(const float4*)(zb + (size_t)(cg * 32 + cc + u) * S);
#pragma unroll
      for (int u = 0; u < 8; u += 2) {
        int c = cg * 32 + cc + u;
#pragma unroll
        for (int k = 0; k < 4; ++k) {
          union { _Float16 h[2]; uint32_t u32; } p;
          p.h[0] = (_Float16)((&v[u].x)[k]);
          p.h[1] = (_Float16)((&v[u + 1].x)[k]);
          *(uint32_t*)(&zA[(tok4 + k) * 264 + c]) = p.u32;
        }
      }
    }
  }
  __syncthreads();

  // A-frags register-resident: af[stripe][kstep]
  half8 af[2][8];
#pragma unroll
  for (int s = 0; s < 2; ++s)
#pragma unroll
    for (int ks = 0; ks < 8; ++ks)
      af[s][ks] = *(const half8*)(&zA[(w * 32 + s * 16 + mrow) * 264 + ks * 32 + quad * 8]);

  __syncthreads();                     // zA dead -> first 64KB becomes B dbuf

  float m1[2][4], m2[2][4];
  int j1[2][4];
#pragma unroll
  for (int s = 0; s < 2; ++s)
#pragma unroll
    for (int r = 0; r < 4; ++r) { m1[s][r] = 3.4e38f; m2[s][r] = 3.4e38f; j1[s][r] = 0; }

  int tile = w >> 1;                   // 0..3: tile of chunk this wave stages
  int khalf = (w & 1) * 4;             // ks range 0..3 / 4..7

  // prologue: stage chunk 0 (tiles 0..3; wave pair per tile, 4KB each)
  {
    const half8* g = (const half8*)embf + ((size_t)(tile * 8 + khalf)) * 64 + lane;
    half8 st[4];
#pragma unroll
    for (int i = 0; i < 4; ++i) st[i] = g[i * 64];
    _Float16* l = (_Float16*)(smem + tile * 8192);
#pragma unroll
    for (int i = 0; i < 4; ++i) *(half8*)(l + (khalf + i) * 512 + lane * 8) = st[i];
  }
  __syncthreads();

  int buf = 0;
  for (int chunk = 0; chunk < 16; ++chunk) {
    // T14: issue next chunk's global loads BEFORE compute (hide L2 latency)
    half8 st[4];
    bool pf = chunk < 15;
    if (pf) {
      const half8* g = (const half8*)embf +
          ((size_t)(((chunk + 1) * 4 + tile) * 8 + khalf)) * 64 + lane;
#pragma unroll
      for (int i = 0; i < 4; ++i) st[i] = g[i * 64];
    }

    // compute 4 tiles from buf (B values bit-identical to the L2-direct path)
#pragma unroll
    for (int ntl = 0; ntl < 4; ++ntl) {
      int nt = chunk * 4 + ntl;
      const half8* pb = (const half8*)(smem + buf * 32768 + ntl * 8192) + lane;
      floatx4 acc0 = {0.f, 0.f, 0.f, 0.f}, acc1 = {0.f, 0.f, 0.f, 0.f};
#pragma unroll
      for (int ks = 0; ks < 8; ++ks) {
        half8 bf = pb[ks * 64];
        acc0 = __builtin_amdgcn_mfma_f32_16x16x32_f16(af[0][ks], bf, acc0, 0, 0, 0);
        acc1 = __builtin_amdgcn_mfma_f32_16x16x32_f16(af[1][ks], bf, acc1, 0, 0, 0);
      }
      int j = nt * 16 + mrow;
      float Bj = en_s[j];              // ||z||^2 constant per token -> dropped
#pragma unroll
      for (int r = 0; r < 4; ++r) {
        // lattice-equivalent to the if/elif top-2 update (ties: m2:=m1, flagged)
        float d0 = Bj - 2.f * acc0[r];
        float d1 = Bj - 2.f * acc1[r];
        bool l0 = d0 < m1[0][r];
        m2[0][r] = fminf(m2[0][r], fmaxf(m1[0][r], d0));
        j1[0][r] = l0 ? j : j1[0][r];
        m1[0][r] = fminf(m1[0][r], d0);
        bool l1 = d1 < m1[1][r];
        m2[1][r] = fminf(m2[1][r], fmaxf(m1[1][r], d1));
        j1[1][r] = l1 ? j : j1[1][r];
        m1[1][r] = fminf(m1[1][r], d1);
      }
    }

    // land the prefetched tile into the other buffer
    if (pf) {
      _Float16* l = (_Float16*)(smem + (buf ^ 1) * 32768 + tile * 8192);
#pragma unroll
      for (int i = 0; i < 4; ++i) *(half8*)(l + (khalf + i) * 512 + lane * 8) = st[i];
    }
    __syncthreads();
    buf ^= 1;
  }

  // merge across the 16 lanes of each quad (same tokens, different codes)
#pragma unroll
  for (int d = 1; d < 16; d <<= 1) {
#pragma unroll
    for (int s = 0; s < 2; ++s)
#pragma unroll
      for (int r = 0; r < 4; ++r) {
        float om1 = __shfl_xor(m1[s][r], d, 64);
        float om2 = __shfl_xor(m2[s][r], d, 64);
        int oj = __shfl_xor(j1[s][r], d, 64);
        float hi;
        if (om1 < m1[s][r] || (om1 == m1[s][r] && oj < j1[s][r])) {
          hi = m1[s][r]; m1[s][r] = om1; j1[s][r] = oj;
        } else hi = om1;                 // equal-m1 merges force m2==m1 -> flagged
        m2[s][r] = fminf(m2[s][r], fminf(om2, hi));
      }
  }

  if (mrow == 0) {
#pragma unroll
    for (int s = 0; s < 2; ++s)
#pragma unroll
      for (int r = 0; r < 4; ++r) {
        int tok = w * 32 + s * 16 + quad * 4 + r;
        out_idx[t0 + tok] = (float)j1[s][r];
        if (m2[s][r] - m1[s][r] < TAU) {
          int p = atomicAdd(&loc_cnt, 1);
          loc_tok[p] = tok;
        }
      }
  }
  __syncthreads();
  if (tid == 0) loc_base = (loc_cnt > 0) ? atomicAdd(amb_cnt, loc_cnt) : 0;
  __syncthreads();

  // compact copy-out: one coalesced 1KB zamb row per ambiguous token.
  // 512 threads: ch = tid&255 channel, pair = tid>>8 handles alternate rows.
  int cnt = loc_cnt;
  int base = loc_base;
  int ch = tid & 255;
  int pair = tid >> 8;
  const float* zcol = z + (size_t)b * ED * S + s0;
  for (int k = pair; k < cnt; k += 2) {
    int lt = loc_tok[k];
    int gpos = base + k;
    if (gpos < TOKENS) {
      if (ch == 0) amb_list[gpos] = t0 + lt;
      if (gpos < zcap)
        zamb[(size_t)gpos * ED + ch] = zcol[(size_t)ch * S + lt];
    }
  }
}

// ---------------- exact-np rescan: 8 tokens/tile, code range SPLIT x2 ---------
// Work item = (tile, half): block handles 8 tokens x 512 codes, 2 codes/thread.
// A (= ||z||^2) computed per tile by 8 threads running the IDENTICAL
// ascending-c fmaf chain from the LDS copy of the exact fp32 z row. Cross-block
// merge via order-preserving u32 transform packed with code idx -> u64
// atomicMin (== lex-(d,j) min == numpy first-index argmin; -0.0 impossible).
#define RT 8
__global__ void __launch_bounds__(256)
k_rescan(const float* __restrict__ z, const float* __restrict__ embT,
         const float* __restrict__ en, const int* __restrict__ amb_cnt,
         const int* __restrict__ amb_list, const float* __restrict__ zamb,
         int zcap, unsigned long long* __restrict__ packed) {
#pragma clang fp contract(off)
  __shared__ float zs[RT][256];
  __shared__ float As_s[RT];
  __shared__ float m1s[RT][256];
  __shared__ int   jms[RT][256];
  int n = *amb_cnt;
  if (n > TOKENS) n = TOKENS;
  int nwork = ((n + RT - 1) / RT) * 2;
  int tid = threadIdx.x;

  for (int idx = blockIdx.x; idx < nwork; idx += gridDim.x) {
    int tile = idx >> 1;
    int half = idx & 1;
    int j0 = half * 512 + tid * 2;
    __syncthreads();                       // protect zs/m1s reuse across tiles
#pragma unroll
    for (int it = 0; it < RT; ++it) {
      int i = tile * RT + it;
      int li = i < n ? i : n - 1;
      if (li < zcap) {
        zs[it][tid] = zamb[(size_t)li * ED + tid];       // coalesced row
      } else {
        int t = amb_list[li];
        int b = t >> 15, s = t & 32767;
        zs[it][tid] = z[(size_t)b * ED * S + (size_t)tid * S + s];
      }
    }
    __syncthreads();
    if (tid < RT) {                        // exact ascending-c ||z||^2 chain
      float Av = 0.f;
      for (int c = 0; c < ED; c += 4) {
        float4 zv = *(const float4*)(&zs[tid][c]);
        Av = fmaf(zv.x, zv.x, Av); Av = fmaf(zv.y, zv.y, Av);
        Av = fmaf(zv.z, zv.z, Av); Av = fmaf(zv.w, zv.w, Av);
      }
      As_s[tid] = Av;
    }
    __syncthreads();

    float A[RT];
#pragma unroll
    for (int it = 0; it < RT; ++it) A[it] = As_s[it];

    float a0[RT], a1[RT];
#pragma unroll
    for (int tk = 0; tk < RT; ++tk) { a0[tk] = 0.f; a1[tk] = 0.f; }
    for (int c = 0; c < ED; c += 4) {
      // q{0..3}.x/.y = codes j0/j0+1 at channels c..c+3 (coalesced)
      float2 q0 = *(const float2*)(embT + (size_t)(c + 0) * NE + j0);
      float2 q1 = *(const float2*)(embT + (size_t)(c + 1) * NE + j0);
      float2 q2 = *(const float2*)(embT + (size_t)(c + 2) * NE + j0);
      float2 q3 = *(const float2*)(embT + (size_t)(c + 3) * NE + j0);
#pragma unroll
      for (int tk = 0; tk < RT; ++tk) {
        float4 zv = *(const float4*)(&zs[tk][c]);
        a0[tk] = fmaf(zv.x, q0.x, a0[tk]); a0[tk] = fmaf(zv.y, q1.x, a0[tk]);
        a0[tk] = fmaf(zv.z, q2.x, a0[tk]); a0[tk] = fmaf(zv.w, q3.x, a0[tk]);
        a1[tk] = fmaf(zv.x, q0.y, a1[tk]); a1[tk] = fmaf(zv.y, q1.y, a1[tk]);
        a1[tk] = fmaf(zv.z, q2.y, a1[tk]); a1[tk] = fmaf(zv.w, q3.y, a1[tk]);
      }
    }

    float e0n = en[j0 + 0], e1n = en[j0 + 1];
#pragma unroll
    for (int tk = 0; tk < RT; ++tk) {
      float d0 = (A[tk] + e0n) - 2.f * a0[tk];
      float d1 = (A[tk] + e1n) - 2.f * a1[tk];
      float bm = d0; int bi = j0;
      if (d1 < bm) { bm = d1; bi = j0 + 1; }
      m1s[tk][tid] = bm; jms[tk][tid] = bi;
    }
    __syncthreads();

    for (int off = 128; off > 0; off >>= 1) {
      if (tid < off) {
#pragma unroll
        for (int tk = 0; tk < RT; ++tk) {
          float dv = m1s[tk][tid + off]; int jv = jms[tk][tid + off];
          float dc = m1s[tk][tid];       int jc = jms[tk][tid];
          if (dv < dc || (dv == dc && jv < jc)) {
            m1s[tk][tid] = dv; jms[tk][tid] = jv;
          }
        }
      }
      __syncthreads();
    }

    if (tid < RT) {
      int i = tile * RT + tid;
      if (i < n) {
        uint32_t ub = __float_as_uint(m1s[tid][0]);
        ub = (ub & 0x80000000u) ? ~ub : (ub | 0x80000000u);
        unsigned long long v =
            ((unsigned long long)ub << 32) | (unsigned)jms[tid][0];
        atomicMin(&packed[i], v);
      }
    }
  }
}

// ---------------- decode packed lex-min -> out_idx ----------------
__global__ void __launch_bounds__(256)
k_dec(const int* __restrict__ amb_cnt, const int* __restrict__ amb_list,
      const unsigned long long* __restrict__ packed,
      float* __restrict__ out_idx) {
  int n = *amb_cnt;
  if (n > TOKENS) n = TOKENS;
  for (int i = blockIdx.x * 256 + threadIdx.x; i < n; i += gridDim.x * 256)
    out_idx[amb_list[i]] = (float)(unsigned)(packed[i] & 0xffffffffULL);
}

// ---------------- epilogue: z_q gather + loss + sampled ----------------
// 256 tokens/block, 512 thr; thread owns 4 consecutive tokens x 32 channels.
// z read and zq write are float4 along s -> 1KB contiguous per wave instr.
__global__ void __launch_bounds__(512)
k_epi(const float* __restrict__ z, const float* __restrict__ emb,
      const float* __restrict__ idxf, float* __restrict__ out_zq,
      float* __restrict__ out_samp, float* __restrict__ out_loss) {
  __shared__ float red[512];
  int tid = threadIdx.x;
  int tg = tid & 63;                   // token quad id
  int w = tid >> 6;                    // 0..7: channel group of 32
  int t0 = blockIdx.x * 256;
  int b = t0 >> 15;                    // 32768 % 256 == 0: no straddle
  int s0 = t0 & 32767;
  int tok4 = tg * 4;

  int jm0 = (int)idxf[t0 + tok4 + 0];
  int jm1 = (int)idxf[t0 + tok4 + 1];
  int jm2 = (int)idxf[t0 + tok4 + 2];
  int jm3 = (int)idxf[t0 + tok4 + 3];
  if (w == 0) {                        // idx < 1024 -> always row 0
    out_samp[jm0] = 1.0f; out_samp[jm1] = 1.0f;
    out_samp[jm2] = 1.0f; out_samp[jm3] = 1.0f;
  }

  const float* zb = z + (size_t)b * ED * S + s0 + tok4;
  float* zqb = out_zq + (size_t)b * ED * S + s0 + tok4;
  const float* e0r = emb + (size_t)jm0 * ED;
  const float* e1r = emb + (size_t)jm1 * ED;
  const float* e2r = emb + (size_t)jm2 * ED;
  const float* e3r = emb + (size_t)jm3 * ED;
  float l0 = 0.f, l1 = 0.f, l2 = 0.f, l3 = 0.f;
  for (int i = 0; i < 32; ++i) {
    int c = w * 32 + i;
    float4 zv = *(const float4*)(zb + (size_t)c * S);
    float e0 = e0r[c], e1 = e1r[c], e2 = e2r[c], e3 = e3r[c];
    float4 q; q.x = e0; q.y = e1; q.z = e2; q.w = e3;
    *(float4*)(zqb + (size_t)c * S) = q;
    float d0 = e0 - zv.x, d1 = e1 - zv.y, d2 = e2 - zv.z, d3 = e3 - zv.w;
    l0 = fmaf(d0, d0, l0); l1 = fmaf(d1, d1, l1);
    l2 = fmaf(d2, d2, l2); l3 = fmaf(d3, d3, l3);
  }
  red[tid] = (l0 + l1) + (l2 + l3);
  __syncthreads();
  for (int off = 256; off > 0; off >>= 1) {
    if (tid < off) red[tid] += red[tid + off];
    __syncthreads();
  }
  if (tid == 0)
    atomicAdd(out_loss, red[0] * (1.2f / 16777216.0f));  // (1+BETA)*mean
}

// ---------------- codebook self-distance: LDS-tiled fp32 GEMM ----------------
__global__ void __launch_bounds__(256)
k_cd(const float* __restrict__ emb, const float* __restrict__ en,
     float* __restrict__ cd) {
  __shared__ float At[64 * 260];
  __shared__ float Bt[64 * 260];
  int bi = blockIdx.x >> 4, bj = blockIdx.x & 15;
  int tid = threadIdx.x;
  const float4* ev = (const float4*)emb;
  for (int idx = tid; idx < 64 * 64; idx += 256) {
    int row = idx >> 6, c4 = idx & 63;
    *(float4*)(&At[row * 260 + c4 * 4]) = ev[(size_t)(bi * 64 + row) * 64 + c4];
    *(float4*)(&Bt[row * 260 + c4 * 4]) = ev[(size_t)(bj * 64 + row) * 64 + c4];
  }
  __syncthreads();
  int ti = tid & 15, tj = tid >> 4;
  float acc[4][4] = {};
  for (int c = 0; c < ED; c += 4) {
    float4 a[4], bq[4];
#pragma unroll
    for (int p = 0; p < 4; ++p) a[p] = *(const float4*)(&At[(ti * 4 + p) * 260 + c]);
#pragma unroll
    for (int q = 0; q < 4; ++q) bq[q] = *(const float4*)(&Bt[(tj * 4 + q) * 260 + c]);
#pragma unroll
    for (int p = 0; p < 4; ++p)
#pragma unroll
      for (int q = 0; q < 4; ++q) {
        acc[p][q] = fmaf(a[p].x, bq[q].x, acc[p][q]);
        acc[p][q] = fmaf(a[p].y, bq[q].y, acc[p][q]);
        acc[p][q] = fmaf(a[p].z, bq[q].z, acc[p][q]);
        acc[p][q] = fmaf(a[p].w, bq[q].w, acc[p][q]);
      }
  }
#pragma unroll
  for (int p = 0; p < 4; ++p)
#pragma unroll
    for (int q = 0; q < 4; ++q) {
      int i = bi * 64 + ti * 4 + p;
      int j = bj * 64 + tj * 4 + q;
      cd[(size_t)i * NE + j] = (en[i] + en[j]) - 2.f * acc[p][q];
    }
}

// ---------------- fused cd stats: colstats (blocks 0..63) + var (64..1087) ----
__global__ void __launch_bounds__(256)
k_cdpost(const float* __restrict__ cd, float* __restrict__ out_md,
         float* __restrict__ out_mv) {
  __shared__ float s1[256], s2[256];
  __shared__ float red[256];
  int blk = blockIdx.x, tid = threadIdx.x;
  if (blk < 64) {
    int j = blk * 16 + (tid & 15);
    int chunk = tid >> 4;
    float m1 = 3.4e38f, m2 = 3.4e38f;
    int r0 = chunk * 64;
    for (int r = r0; r < r0 + 64; ++r) {
      float v = cd[(size_t)r * NE + j];
      if (v < m1) { m2 = m1; m1 = v; }
      else if (v < m2) { m2 = v; }
    }
    s1[tid] = m1; s2[tid] = m2;
    __syncthreads();
    if (chunk == 0) {
      for (int cc = 1; cc < 16; ++cc) {
        float n1 = s1[cc * 16 + tid], n2 = s2[cc * 16 + tid];
        float lo = fminf(m1, n1);
        float hi = fmaxf(m1, n1);
        m2 = fminf(hi, fminf(m2, n2));
        m1 = lo;
      }
      atomicAdd(out_md, m2 * (1.0f / 1024.0f));
    }
  } else {
    int i = blk - 64;
    const float* row = cd + (size_t)i * NE;
    float s = row[tid] + row[tid + 256] + row[tid + 512] + row[tid + 768];
    red[tid] = s;
    __syncthreads();
    for (int off = 128; off > 0; off >>= 1) {
      if (tid < off) red[tid] += red[tid + off];
      __syncthreads();
    }
    float mean = red[0] * (1.0f / 1024.0f);
    __syncthreads();
    float d0 = row[tid] - mean, d1 = row[tid + 256] - mean,
          d2 = row[tid + 512] - mean, d3 = row[tid + 768] - mean;
    red[tid] = d0 * d0 + d1 * d1 + d2 * d2 + d3 * d3;
    __syncthreads();
    for (int off = 128; off > 0; off >>= 1) {
      if (tid < off) red[tid] += red[tid + off];
      __syncthreads();
    }
    if (tid == 0)
      atomicAdd(out_mv, red[0] * (1.0f / 1023.0f) * (1.0f / 1024.0f));
  }
}

extern "C" void kernel_launch(void* const* d_in, const int* in_sizes, int n_in,
                              void* d_out, int out_size, void* d_ws, size_t ws_size,
                              hipStream_t stream) {
  const float* z   = (const float*)d_in[0];
  const float* emb = (const float*)d_in[1];
  float* out = (float*)d_out;

  float* cd = (float*)d_ws;                       // 4 MiB
  float* en = cd + (size_t)NE * NE;               // 4 KiB
  _Float16* embf = (_Float16*)(en + NE);          // 512 KiB fragment-ordered fp16
  int* amb_cnt = (int*)(embf + (size_t)NE * ED);
  int* amb_list = amb_cnt + 16;                   // TOKENS ints (256 KiB)
  unsigned long long* packed =
      (unsigned long long*)(amb_list + TOKENS);   // 512 KiB lex-min cells
  float* embT = (float*)(packed + TOKENS);        // 1 MiB transposed codebook
  float* zamb = embT + (size_t)ED * NE;           // compacted z rows (1KB each)

  size_t base_bytes = (size_t)((char*)zamb - (char*)d_ws);
  int zcap = 0;
  if (ws_size > base_bytes) {
    size_t rows = (ws_size - base_bytes) / ((size_t)ED * sizeof(float));
    zcap = rows > (size_t)ZCAP_MAX ? ZCAP_MAX : (int)rows;
  }

  hipMemsetAsync(out + OFF_LOSS, 0,
                 (size_t)(out_size - OFF_LOSS) * sizeof(float), stream);

  k_prep<<<644, 256, 0, stream>>>(emb, en, embf, embT, packed, amb_cnt);
  k_filter<<<TOKENS / 256, 512, 0, stream>>>(z, embf, en, out + OFF_IDX,
                                             amb_cnt, amb_list, zamb, zcap);
  k_rescan<<<4096, 256, 0, stream>>>(z, embT, en, amb_cnt, amb_list,
                                     zamb, zcap, packed);
  k_dec<<<64, 256, 0, stream>>>(amb_cnt, amb_list, packed, out + OFF_IDX);
  k_epi<<<TOKENS / 256, 512, 0, stream>>>(z, emb, out + OFF_IDX,
                                          out, out + OFF_SAMP, out + OFF_LOSS);
  k_cd<<<256, 256, 0, stream>>>(emb, en, cd);
  k_cdpost<<<1088, 256, 0, stream>>>(cd, out + OFF_MD, out + OFF_MV);
}